// Round 1
// baseline (5156.299 us; speedup 1.0000x reference)
//
#include <hip/hip_runtime.h>
#include <hip/hip_bf16.h>

#define N_NODES 19000
#define N_EDGES 600000
#define BATCH   4096
#define GNN_D   256
#define H_D     512
#define MID_D   2048
#define L_N     6
#define C_N     3
#define R_D     512
#define G_N     6640
#define LN_EPS  1e-5f

// ---------------- utility kernels ----------------

__global__ void zero_f4_kernel(float* __restrict__ p, int n4) {
  int i = blockIdx.x * blockDim.x + threadIdx.x;
  if (i < n4) ((float4*)p)[i] = make_float4(0.f, 0.f, 0.f, 0.f);
}

// one wave per edge: agg[dst] += cache[src] * w   (256 floats/row, 4/lane)
__global__ __launch_bounds__(256) void scatter_edges_kernel(
    const float* __restrict__ cache, const int* __restrict__ ei,
    const float* __restrict__ ew, float* __restrict__ agg) {
  int gid = blockIdx.x * blockDim.x + threadIdx.x;
  int e = gid >> 6;
  int lane = gid & 63;
  if (e >= N_EDGES) return;
  int src = ei[e];
  int dst = ei[N_EDGES + e];
  float w = ew[e];
  float4 v = *(const float4*)(cache + (size_t)src * GNN_D + lane * 4);
  float* a = agg + (size_t)dst * GNN_D + lane * 4;
  atomicAdd(a + 0, v.x * w);
  atomicAdd(a + 1, v.y * w);
  atomicAdd(a + 2, v.z * w);
  atomicAdd(a + 3, v.w * w);
}

// gather (with -1 fallback) + LayerNorm over 256, one block per row
__global__ __launch_bounds__(256) void gather_ln_kernel(
    const float* __restrict__ node_emb, const float* __restrict__ fallback,
    const int* __restrict__ idx, const float* __restrict__ scale,
    const float* __restrict__ bias, float* __restrict__ out) {
  int b = blockIdx.x, t = threadIdx.x;
  int id = idx[b];
  float v = (id >= 0) ? node_emb[(size_t)id * GNN_D + t] : fallback[t];
  float s = v, q = v * v;
#pragma unroll
  for (int o = 32; o > 0; o >>= 1) { s += __shfl_down(s, o); q += __shfl_down(q, o); }
  __shared__ float ls[4], lq[4];
  int wv = t >> 6, ln = t & 63;
  if (ln == 0) { ls[wv] = s; lq[wv] = q; }
  __syncthreads();
  s = ls[0] + ls[1] + ls[2] + ls[3];
  q = lq[0] + lq[1] + lq[2] + lq[3];
  float mu = s * (1.f / GNN_D);
  float var = q * (1.f / GNN_D) - mu * mu;
  float r = rsqrtf(var + LN_EPS);
  out[(size_t)b * GNN_D + t] = (v - mu) * r * scale[t] + bias[t];
}

// LayerNorm over 512, one block (256 thr) per row, 2 elems/thread
__global__ __launch_bounds__(256) void ln512_kernel(
    const float* __restrict__ x, const float* __restrict__ scale,
    const float* __restrict__ bias, float* __restrict__ out) {
  int b = blockIdx.x, t = threadIdx.x;
  const float* xr = x + (size_t)b * H_D;
  float v0 = xr[t];
  float v1 = xr[256 + t];
  float s = v0 + v1, q = v0 * v0 + v1 * v1;
#pragma unroll
  for (int o = 32; o > 0; o >>= 1) { s += __shfl_down(s, o); q += __shfl_down(q, o); }
  __shared__ float ls[4], lq[4];
  int wv = t >> 6, ln = t & 63;
  if (ln == 0) { ls[wv] = s; lq[wv] = q; }
  __syncthreads();
  s = ls[0] + ls[1] + ls[2] + ls[3];
  q = lq[0] + lq[1] + lq[2] + lq[3];
  float mu = s * (1.f / H_D);
  float var = q * (1.f / H_D) - mu * mu;
  float r = rsqrtf(var + LN_EPS);
  float* orow = out + (size_t)b * H_D;
  orow[t]       = (v0 - mu) * r * scale[t]       + bias[t];
  orow[256 + t] = (v1 - mu) * r * scale[256 + t] + bias[256 + t];
}

// ---------------- fp32 tiled GEMM: C = act(A @ W^T + bias + addC) ----------------
// A: [M,K] row-major, W: [N,K] row-major. Tile BM=NQR*64, BN=NQC*64, BK=16.
// 256 threads (16x16), micro-tile (4*NQR)x(4*NQC) split into 64-wide quadrants
// so LDS reads and global stores are float4.
__device__ inline float gelu_exact(float x) {
  return 0.5f * x * (1.f + erff(x * 0.70710678118654752f));
}

template <int NQR, int NQC, int ACT>  // ACT: 0 none, 1 relu, 2 gelu
__global__ __launch_bounds__(256) void gemm_f32_kernel(
    const float* __restrict__ A, const float* __restrict__ W,
    const float* __restrict__ bias, const float* __restrict__ addC,
    float* __restrict__ C, int M, int N, int K) {
  constexpr int BM = NQR * 64;
  constexpr int BN = NQC * 64;
  __shared__ __align__(16) float sA[16][BM];
  __shared__ __align__(16) float sB[16][BN];

  const int tid = threadIdx.x;
  const int tx = tid & 15, ty = tid >> 4;
  const int bm = blockIdx.x * BM;
  const int bn = blockIdx.y * BN;

  float acc[NQR * 4][NQC * 4];
#pragma unroll
  for (int i = 0; i < NQR * 4; ++i)
#pragma unroll
    for (int j = 0; j < NQC * 4; ++j) acc[i][j] = 0.f;

  for (int k0 = 0; k0 < K; k0 += 16) {
#pragma unroll
    for (int q = 0; q < NQR; ++q) {
      int li = tid + q * 256;       // 0 .. BM*4-1
      int row = li >> 2;            // 0 .. BM-1
      int kq = (li & 3) << 2;       // 0,4,8,12
      int ar = min(bm + row, M - 1);
      float4 av = *(const float4*)(A + (size_t)ar * K + k0 + kq);
      sA[kq + 0][row] = av.x; sA[kq + 1][row] = av.y;
      sA[kq + 2][row] = av.z; sA[kq + 3][row] = av.w;
    }
#pragma unroll
    for (int q = 0; q < NQC; ++q) {
      int li = tid + q * 256;
      int row = li >> 2;
      int kq = (li & 3) << 2;
      int wr = min(bn + row, N - 1);
      float4 wv = *(const float4*)(W + (size_t)wr * K + k0 + kq);
      sB[kq + 0][row] = wv.x; sB[kq + 1][row] = wv.y;
      sB[kq + 2][row] = wv.z; sB[kq + 3][row] = wv.w;
    }
    __syncthreads();
#pragma unroll
    for (int kk = 0; kk < 16; ++kk) {
      float4 av[NQR], bv[NQC];
#pragma unroll
      for (int q = 0; q < NQR; ++q) av[q] = *(const float4*)&sA[kk][q * 64 + ty * 4];
#pragma unroll
      for (int q = 0; q < NQC; ++q) bv[q] = *(const float4*)&sB[kk][q * 64 + tx * 4];
      const float* ap = (const float*)av;
      const float* bp = (const float*)bv;
#pragma unroll
      for (int i = 0; i < NQR * 4; ++i)
#pragma unroll
        for (int j = 0; j < NQC * 4; ++j) acc[i][j] += ap[i] * bp[j];
    }
    __syncthreads();
  }

#pragma unroll
  for (int qr = 0; qr < NQR; ++qr) {
#pragma unroll
    for (int i = 0; i < 4; ++i) {
      int row = bm + qr * 64 + ty * 4 + i;
      if (row >= M) continue;
#pragma unroll
      for (int qc = 0; qc < NQC; ++qc) {
        int col = bn + qc * 64 + tx * 4;
        if (col >= N) continue;
        float4 v = make_float4(acc[qr * 4 + i][qc * 4 + 0], acc[qr * 4 + i][qc * 4 + 1],
                               acc[qr * 4 + i][qc * 4 + 2], acc[qr * 4 + i][qc * 4 + 3]);
        if (bias) {
          v.x += bias[col]; v.y += bias[col + 1]; v.z += bias[col + 2]; v.w += bias[col + 3];
        }
        if (addC) {
          float4 ad = *(const float4*)(addC + (size_t)row * N + col);
          v.x += ad.x; v.y += ad.y; v.z += ad.z; v.w += ad.w;
        }
        if (ACT == 1) {
          v.x = fmaxf(v.x, 0.f); v.y = fmaxf(v.y, 0.f);
          v.z = fmaxf(v.z, 0.f); v.w = fmaxf(v.w, 0.f);
        } else if (ACT == 2) {
          v.x = gelu_exact(v.x); v.y = gelu_exact(v.y);
          v.z = gelu_exact(v.z); v.w = gelu_exact(v.w);
        }
        *(float4*)(C + (size_t)row * N + col) = v;
      }
    }
  }
}

template <int NQR, int NQC, int ACT>
static void launch_gemm(const float* A, const float* W, const float* bias,
                        const float* addC, float* C, int M, int N, int K,
                        hipStream_t stream) {
  dim3 grid((M + NQR * 64 - 1) / (NQR * 64), (N + NQC * 64 - 1) / (NQC * 64));
  gemm_f32_kernel<NQR, NQC, ACT><<<grid, 256, 0, stream>>>(A, W, bias, addC, C, M, N, K);
}

// ---------------- launch ----------------

extern "C" void kernel_launch(void* const* d_in, const int* in_sizes, int n_in,
                              void* d_out, int out_size, void* d_ws, size_t ws_size,
                              hipStream_t stream) {
  const int*   node_indices = (const int*)d_in[0];
  const int*   edge_index   = (const int*)d_in[1];
  const float* edge_weight  = (const float*)d_in[2];
  const float* cache        = (const float*)d_in[3];
  const float* w_root       = (const float*)d_in[4];
  const float* w_neigh      = (const float*)d_in[5];
  const float* w_post       = (const float*)d_in[6];
  const float* b_post       = (const float*)d_in[7];
  const float* fallback     = (const float*)d_in[8];
  const float* ln_in_scale  = (const float*)d_in[9];
  const float* ln_in_bias   = (const float*)d_in[10];
  const float* w_in         = (const float*)d_in[11];
  const float* rb_ln_scale  = (const float*)d_in[12];
  const float* rb_ln_bias   = (const float*)d_in[13];
  const float* rb_fc1       = (const float*)d_in[14];
  const float* rb_fc2       = (const float*)d_in[15];
  const float* w_bil        = (const float*)d_in[16];
  const float* gene         = (const float*)d_in[17];
  float* out = (float*)d_out;

  // workspace layout (floats)
  float* ws     = (float*)d_ws;
  float* agg    = ws;                      // 19000*256 = 4,864,000
  float* tmp    = agg    + (size_t)N_NODES * GNN_D;  // x / tmp, 4,864,000
  float* nemb   = tmp    + (size_t)N_NODES * GNN_D;  // 4,864,000
  float* pertln = nemb   + (size_t)N_NODES * GNN_D;  // 4096*256
  float* h      = pertln + (size_t)BATCH * GNN_D;    // 4096*512
  float* yln    = h      + (size_t)BATCH * H_D;      // 4096*512
  float* ymid   = yln    + (size_t)BATCH * H_D;      // 4096*2048
  float* blin   = ymid   + (size_t)BATCH * MID_D;    // 4096*1536

  // 1) agg = 0 ; scatter edges
  {
    int n4 = N_NODES * GNN_D / 4;
    zero_f4_kernel<<<(n4 + 255) / 256, 256, 0, stream>>>(agg, n4);
    long long tot = (long long)N_EDGES * 64;
    scatter_edges_kernel<<<(int)((tot + 255) / 256), 256, 0, stream>>>(
        cache, edge_index, edge_weight, agg);
  }

  // 2) graph tail GEMMs
  launch_gemm<2, 1, 0>(cache, w_root,  nullptr, nullptr, tmp,  N_NODES, GNN_D, GNN_D, stream);
  launch_gemm<2, 1, 1>(agg,   w_neigh, nullptr, tmp,     tmp,  N_NODES, GNN_D, GNN_D, stream);
  launch_gemm<2, 1, 0>(tmp,   w_post,  b_post,  nullptr, nemb, N_NODES, GNN_D, GNN_D, stream);

  // 3) gather + input LN, input proj
  gather_ln_kernel<<<BATCH, 256, 0, stream>>>(nemb, fallback, node_indices,
                                              ln_in_scale, ln_in_bias, pertln);
  launch_gemm<2, 1, 0>(pertln, w_in, nullptr, nullptr, h, BATCH, H_D, GNN_D, stream);

  // 4) residual blocks
  for (int i = 0; i < L_N; ++i) {
    ln512_kernel<<<BATCH, 256, 0, stream>>>(h, rb_ln_scale + (size_t)i * H_D,
                                            rb_ln_bias + (size_t)i * H_D, yln);
    launch_gemm<2, 2, 2>(yln,  rb_fc1 + (size_t)i * MID_D * H_D, nullptr, nullptr,
                         ymid, BATCH, MID_D, H_D, stream);
    launch_gemm<2, 1, 0>(ymid, rb_fc2 + (size_t)i * H_D * MID_D, nullptr, h,
                         h,    BATCH, H_D, MID_D, stream);
  }

  // 5) bilinear head + gene einsum (as GEMM, writes d_out directly)
  launch_gemm<2, 2, 0>(h,    w_bil, nullptr, nullptr, blin, BATCH, C_N * R_D, H_D, stream);
  launch_gemm<2, 2, 0>(blin, gene,  nullptr, nullptr, out,  BATCH * C_N, G_N, R_D, stream);
}

// Round 2
// 1308.175 us; speedup vs baseline: 3.9416x; 3.9416x over previous
//
#include <hip/hip_runtime.h>
#include <hip/hip_bf16.h>

#define N_NODES 19000
#define N_EDGES 600000
#define BATCH   4096
#define GNN_D   256
#define H_D     512
#define MID_D   2048
#define L_N     6
#define C_N     3
#define R_D     512
#define G_N     6640
#define LN_EPS  1e-5f

typedef __attribute__((ext_vector_type(8))) short short8;
typedef __attribute__((ext_vector_type(4))) float f32x4;
typedef __hip_bfloat16 bf16;

// ---------------- utility kernels ----------------

__global__ void zero_f4_kernel(float* __restrict__ p, int n4) {
  int i = blockIdx.x * blockDim.x + threadIdx.x;
  if (i < n4) ((float4*)p)[i] = make_float4(0.f, 0.f, 0.f, 0.f);
}

__global__ void zero_i32_kernel(int* __restrict__ p, int n) {
  int i = blockIdx.x * blockDim.x + threadIdx.x;
  if (i < n) p[i] = 0;
}

__global__ void mark_needed_kernel(const int* __restrict__ idx, int* __restrict__ flags) {
  int i = blockIdx.x * blockDim.x + threadIdx.x;
  if (i < BATCH) {
    int id = idx[i];
    if (id >= 0) flags[id] = 1;
  }
}

__global__ void f32_to_bf16_kernel(const float* __restrict__ in, bf16* __restrict__ out, int n4) {
  int i = blockIdx.x * blockDim.x + threadIdx.x;
  if (i >= n4) return;
  float4 v = ((const float4*)in)[i];
  out[i * 4 + 0] = __float2bfloat16(v.x);
  out[i * 4 + 1] = __float2bfloat16(v.y);
  out[i * 4 + 2] = __float2bfloat16(v.z);
  out[i * 4 + 3] = __float2bfloat16(v.w);
}

// one wave per edge, filtered by needed-destination mask
__global__ __launch_bounds__(256) void scatter_edges_kernel(
    const float* __restrict__ cache, const int* __restrict__ ei,
    const float* __restrict__ ew, const int* __restrict__ flags,
    float* __restrict__ agg) {
  int gid = blockIdx.x * blockDim.x + threadIdx.x;
  int e = gid >> 6;
  int lane = gid & 63;
  if (e >= N_EDGES) return;
  int dst = ei[N_EDGES + e];
  if (!flags[dst]) return;           // ~81% of edges exit here
  int src = ei[e];
  float w = ew[e];
  float4 v = *(const float4*)(cache + (size_t)src * GNN_D + lane * 4);
  float* a = agg + (size_t)dst * GNN_D + lane * 4;
  atomicAdd(a + 0, v.x * w);
  atomicAdd(a + 1, v.y * w);
  atomicAdd(a + 2, v.z * w);
  atomicAdd(a + 3, v.w * w);
}

// gather (with -1 fallback) + LayerNorm over 256 -> bf16
__global__ __launch_bounds__(256) void gather_ln_kernel(
    const float* __restrict__ node_emb, const float* __restrict__ fallback,
    const int* __restrict__ idx, const float* __restrict__ scale,
    const float* __restrict__ bias, bf16* __restrict__ out) {
  int b = blockIdx.x, t = threadIdx.x;
  int id = idx[b];
  float v = (id >= 0) ? node_emb[(size_t)id * GNN_D + t] : fallback[t];
  float s = v, q = v * v;
#pragma unroll
  for (int o = 32; o > 0; o >>= 1) { s += __shfl_down(s, o); q += __shfl_down(q, o); }
  __shared__ float ls[4], lq[4];
  int wv = t >> 6, ln = t & 63;
  if (ln == 0) { ls[wv] = s; lq[wv] = q; }
  __syncthreads();
  s = ls[0] + ls[1] + ls[2] + ls[3];
  q = lq[0] + lq[1] + lq[2] + lq[3];
  float mu = s * (1.f / GNN_D);
  float var = q * (1.f / GNN_D) - mu * mu;
  float r = rsqrtf(var + LN_EPS);
  out[(size_t)b * GNN_D + t] = __float2bfloat16((v - mu) * r * scale[t] + bias[t]);
}

// LayerNorm over 512 -> bf16
__global__ __launch_bounds__(256) void ln512_kernel(
    const float* __restrict__ x, const float* __restrict__ scale,
    const float* __restrict__ bias, bf16* __restrict__ out) {
  int b = blockIdx.x, t = threadIdx.x;
  const float* xr = x + (size_t)b * H_D;
  float v0 = xr[t];
  float v1 = xr[256 + t];
  float s = v0 + v1, q = v0 * v0 + v1 * v1;
#pragma unroll
  for (int o = 32; o > 0; o >>= 1) { s += __shfl_down(s, o); q += __shfl_down(q, o); }
  __shared__ float ls[4], lq[4];
  int wv = t >> 6, ln = t & 63;
  if (ln == 0) { ls[wv] = s; lq[wv] = q; }
  __syncthreads();
  s = ls[0] + ls[1] + ls[2] + ls[3];
  q = lq[0] + lq[1] + lq[2] + lq[3];
  float mu = s * (1.f / H_D);
  float var = q * (1.f / H_D) - mu * mu;
  float r = rsqrtf(var + LN_EPS);
  bf16* orow = out + (size_t)b * H_D;
  orow[t]       = __float2bfloat16((v0 - mu) * r * scale[t]       + bias[t]);
  orow[256 + t] = __float2bfloat16((v1 - mu) * r * scale[256 + t] + bias[256 + t]);
}

__device__ inline float gelu_exact(float x) {
  return 0.5f * x * (1.f + erff(x * 0.70710678118654752f));
}

// ---------------- fp32 tiled GEMM (graph tail only) ----------------

template <int NQR, int NQC, int ACT>  // ACT: 0 none, 1 relu
__global__ __launch_bounds__(256) void gemm_f32_kernel(
    const float* __restrict__ A, const float* __restrict__ W,
    const float* __restrict__ bias, const float* __restrict__ addC,
    float* __restrict__ C, int M, int N, int K) {
  constexpr int BM = NQR * 64;
  constexpr int BN = NQC * 64;
  __shared__ __align__(16) float sA[16][BM];
  __shared__ __align__(16) float sB[16][BN];

  const int tid = threadIdx.x;
  const int tx = tid & 15, ty = tid >> 4;
  const int bm = blockIdx.x * BM;
  const int bn = blockIdx.y * BN;

  float acc[NQR * 4][NQC * 4];
#pragma unroll
  for (int i = 0; i < NQR * 4; ++i)
#pragma unroll
    for (int j = 0; j < NQC * 4; ++j) acc[i][j] = 0.f;

  for (int k0 = 0; k0 < K; k0 += 16) {
#pragma unroll
    for (int q = 0; q < NQR; ++q) {
      int li = tid + q * 256;
      int row = li >> 2;
      int kq = (li & 3) << 2;
      int ar = min(bm + row, M - 1);
      float4 av = *(const float4*)(A + (size_t)ar * K + k0 + kq);
      sA[kq + 0][row] = av.x; sA[kq + 1][row] = av.y;
      sA[kq + 2][row] = av.z; sA[kq + 3][row] = av.w;
    }
#pragma unroll
    for (int q = 0; q < NQC; ++q) {
      int li = tid + q * 256;
      int row = li >> 2;
      int kq = (li & 3) << 2;
      int wr = min(bn + row, N - 1);
      float4 wv = *(const float4*)(W + (size_t)wr * K + k0 + kq);
      sB[kq + 0][row] = wv.x; sB[kq + 1][row] = wv.y;
      sB[kq + 2][row] = wv.z; sB[kq + 3][row] = wv.w;
    }
    __syncthreads();
#pragma unroll
    for (int kk = 0; kk < 16; ++kk) {
      float4 av[NQR], bv[NQC];
#pragma unroll
      for (int q = 0; q < NQR; ++q) av[q] = *(const float4*)&sA[kk][q * 64 + ty * 4];
#pragma unroll
      for (int q = 0; q < NQC; ++q) bv[q] = *(const float4*)&sB[kk][q * 64 + tx * 4];
      const float* ap = (const float*)av;
      const float* bp = (const float*)bv;
#pragma unroll
      for (int i = 0; i < NQR * 4; ++i)
#pragma unroll
        for (int j = 0; j < NQC * 4; ++j) acc[i][j] += ap[i] * bp[j];
    }
    __syncthreads();
  }

#pragma unroll
  for (int qr = 0; qr < NQR; ++qr) {
#pragma unroll
    for (int i = 0; i < 4; ++i) {
      int row = bm + qr * 64 + ty * 4 + i;
      if (row >= M) continue;
#pragma unroll
      for (int qc = 0; qc < NQC; ++qc) {
        int col = bn + qc * 64 + tx * 4;
        if (col >= N) continue;
        float4 v = make_float4(acc[qr * 4 + i][qc * 4 + 0], acc[qr * 4 + i][qc * 4 + 1],
                               acc[qr * 4 + i][qc * 4 + 2], acc[qr * 4 + i][qc * 4 + 3]);
        if (bias) {
          v.x += bias[col]; v.y += bias[col + 1]; v.z += bias[col + 2]; v.w += bias[col + 3];
        }
        if (addC) {
          float4 ad = *(const float4*)(addC + (size_t)row * N + col);
          v.x += ad.x; v.y += ad.y; v.z += ad.z; v.w += ad.w;
        }
        if (ACT == 1) {
          v.x = fmaxf(v.x, 0.f); v.y = fmaxf(v.y, 0.f);
          v.z = fmaxf(v.z, 0.f); v.w = fmaxf(v.w, 0.f);
        }
        *(float4*)(C + (size_t)row * N + col) = v;
      }
    }
  }
}

template <int NQR, int NQC, int ACT>
static void launch_gemm_f32(const float* A, const float* W, const float* bias,
                            const float* addC, float* C, int M, int N, int K,
                            hipStream_t stream) {
  dim3 grid((M + NQR * 64 - 1) / (NQR * 64), (N + NQC * 64 - 1) / (NQC * 64));
  gemm_f32_kernel<NQR, NQC, ACT><<<grid, 256, 0, stream>>>(A, W, bias, addC, C, M, N, K);
}

// ---------------- bf16 MFMA GEMM: C = act(A @ W^T [+ addC]) ----------------
// A: [M,K] bf16 row-major, W: [N,K] bf16 row-major. M % 128 == 0, K % 32 == 0.
// 128x128 tile, BK=32, 4 waves each owning a 64x64 block (4x4 frags of 16x16x32).
// m97 structure: global_load_lds(16B) staging, linear LDS, 2 barriers/K-step.

template <int ACT, int OUT_BF16, int ADDC>  // ACT: 0 none, 2 gelu
__global__ __launch_bounds__(256) void gemm_mfma_kernel(
    const bf16* __restrict__ A, const bf16* __restrict__ W,
    const float* __restrict__ addC, void* __restrict__ Cout,
    int M, int N, int K) {
  __shared__ __align__(16) bf16 sA[128 * 32];
  __shared__ __align__(16) bf16 sB[128 * 32];
  const int tid = threadIdx.x;
  const int lane = tid & 63;
  const int wid = tid >> 6;
  const int wr = wid >> 1, wc = wid & 1;
  const int bm = blockIdx.x * 128, bn = blockIdx.y * 128;

  f32x4 acc[4][4];
#pragma unroll
  for (int m = 0; m < 4; ++m)
#pragma unroll
    for (int n = 0; n < 4; ++n) acc[m][n] = (f32x4){0.f, 0.f, 0.f, 0.f};

  const int rbase = lane & 15;   // fragment row (A) / col (B)
  const int g = lane >> 4;       // k-group

  for (int k0 = 0; k0 < K; k0 += 32) {
#pragma unroll
    for (int i = 0; i < 2; ++i) {
      int li = i * 256 + tid;         // 0..511
      int row = li >> 2;              // 0..127
      int kq = (li & 3) << 3;         // 0,8,16,24 (bf16 elems)
      int ar = bm + row; ar = (ar < M) ? ar : (M - 1);
      int br = bn + row; br = (br < N) ? br : (N - 1);
      __builtin_amdgcn_global_load_lds(
          (const __attribute__((address_space(1))) void*)(A + (size_t)ar * K + k0 + kq),
          (__attribute__((address_space(3))) void*)(sA + li * 8), 16, 0, 0);
      __builtin_amdgcn_global_load_lds(
          (const __attribute__((address_space(1))) void*)(W + (size_t)br * K + k0 + kq),
          (__attribute__((address_space(3))) void*)(sB + li * 8), 16, 0, 0);
    }
    __syncthreads();

    short8 af[4], bfrag[4];
#pragma unroll
    for (int m = 0; m < 4; ++m)
      af[m] = *(const short8*)(sA + (wr * 64 + m * 16 + rbase) * 32 + g * 8);
#pragma unroll
    for (int n = 0; n < 4; ++n)
      bfrag[n] = *(const short8*)(sB + (wc * 64 + n * 16 + rbase) * 32 + g * 8);
#pragma unroll
    for (int m = 0; m < 4; ++m)
#pragma unroll
      for (int n = 0; n < 4; ++n)
        acc[m][n] = __builtin_amdgcn_mfma_f32_16x16x32_bf16(af[m], bfrag[n], acc[m][n], 0, 0, 0);
    __syncthreads();
  }

  // epilogue: C/D frag mapping col=lane&15, row=(lane>>4)*4+reg  [m89-verified]
  const int rb = (lane >> 4) * 4;
  const int cb = lane & 15;
#pragma unroll
  for (int m = 0; m < 4; ++m) {
#pragma unroll
    for (int n = 0; n < 4; ++n) {
      int col = bn + wc * 64 + n * 16 + cb;
      if (col >= N) continue;
      int row0 = bm + wr * 64 + m * 16 + rb;
#pragma unroll
      for (int r = 0; r < 4; ++r) {
        int row = row0 + r;
        if (row >= M) continue;
        float v = acc[m][n][r];
        if (ADDC) v += addC[(size_t)row * N + col];
        if (ACT == 2) v = gelu_exact(v);
        if (OUT_BF16)
          ((bf16*)Cout)[(size_t)row * N + col] = __float2bfloat16(v);
        else
          ((float*)Cout)[(size_t)row * N + col] = v;
      }
    }
  }
}

template <int ACT, int OUT_BF16, int ADDC>
static void launch_mfma(const bf16* A, const bf16* W, const float* addC, void* C,
                        int M, int N, int K, hipStream_t stream) {
  dim3 grid(M / 128, (N + 127) / 128);
  gemm_mfma_kernel<ACT, OUT_BF16, ADDC><<<grid, 256, 0, stream>>>(A, W, addC, C, M, N, K);
}

// ---------------- launch ----------------

extern "C" void kernel_launch(void* const* d_in, const int* in_sizes, int n_in,
                              void* d_out, int out_size, void* d_ws, size_t ws_size,
                              hipStream_t stream) {
  const int*   node_indices = (const int*)d_in[0];
  const int*   edge_index   = (const int*)d_in[1];
  const float* edge_weight  = (const float*)d_in[2];
  const float* cache        = (const float*)d_in[3];
  const float* w_root       = (const float*)d_in[4];
  const float* w_neigh      = (const float*)d_in[5];
  const float* w_post       = (const float*)d_in[6];
  const float* b_post       = (const float*)d_in[7];
  const float* fallback     = (const float*)d_in[8];
  const float* ln_in_scale  = (const float*)d_in[9];
  const float* ln_in_bias   = (const float*)d_in[10];
  const float* w_in         = (const float*)d_in[11];
  const float* rb_ln_scale  = (const float*)d_in[12];
  const float* rb_ln_bias   = (const float*)d_in[13];
  const float* rb_fc1       = (const float*)d_in[14];
  const float* rb_fc2       = (const float*)d_in[15];
  const float* w_bil        = (const float*)d_in[16];
  const float* gene         = (const float*)d_in[17];
  float* out = (float*)d_out;

  // ---- workspace layout (bytes) ----
  char* w = (char*)d_ws;
  const size_t NODE_BUF = (size_t)N_NODES * GNN_D * 4;  // 19,456,000 B
  float* agg  = (float*)(w);
  float* tmp  = (float*)(w + NODE_BUF);
  float* nemb = (float*)(w + 2 * NODE_BUF);
  // reuse agg region after graph GEMM 2 consumes agg:
  bf16* pertln = (bf16*)(w);                         //  2 MB (written after agg dead)
  bf16* blin   = (bf16*)(w + 4u * 1024 * 1024);      // 12.6 MB
  // reuse tmp region after nemb GEMM consumes tmp:
  float* h     = (float*)(w + NODE_BUF);             //  8 MB
  bf16*  yln   = (bf16*)(w + NODE_BUF + 8388608);    //  4 MB
  bf16*  h_bf  = (bf16*)(w + NODE_BUF + 12582912);   //  4 MB
  // reuse nemb region after gather_ln consumes nemb:
  bf16*  ymid  = (bf16*)(w + 2 * NODE_BUF);          // 16.8 MB
  // persistent region (weights etc.) above the three node buffers:
  size_t off = 3 * NODE_BUF;
  bf16* w_in_bf = (bf16*)(w + off); off += (size_t)H_D * GNN_D * 2;
  bf16* fc1_bf  = (bf16*)(w + off); off += (size_t)L_N * MID_D * H_D * 2;
  bf16* fc2_bf  = (bf16*)(w + off); off += (size_t)L_N * H_D * MID_D * 2;
  bf16* wbil_bf = (bf16*)(w + off); off += (size_t)C_N * R_D * H_D * 2;
  bf16* gene_bf = (bf16*)(w + off); off += (size_t)G_N * R_D * 2;
  int*  flags   = (int*)(w + off);  off += (size_t)N_NODES * 4;

  // 0) weight conversions to bf16
  {
    int n4;
    n4 = H_D * GNN_D / 4;
    f32_to_bf16_kernel<<<(n4 + 255) / 256, 256, 0, stream>>>(w_in, w_in_bf, n4);
    n4 = L_N * MID_D * H_D / 4;
    f32_to_bf16_kernel<<<(n4 + 255) / 256, 256, 0, stream>>>(rb_fc1, fc1_bf, n4);
    f32_to_bf16_kernel<<<(n4 + 255) / 256, 256, 0, stream>>>(rb_fc2, fc2_bf, n4);
    n4 = C_N * R_D * H_D / 4;
    f32_to_bf16_kernel<<<(n4 + 255) / 256, 256, 0, stream>>>(w_bil, wbil_bf, n4);
    n4 = G_N * R_D / 4;
    f32_to_bf16_kernel<<<(n4 + 255) / 256, 256, 0, stream>>>(gene, gene_bf, n4);
  }

  // 1) needed-node mask; zero agg; filtered scatter
  {
    int n4 = N_NODES * GNN_D / 4;
    zero_f4_kernel<<<(n4 + 255) / 256, 256, 0, stream>>>(agg, n4);
    zero_i32_kernel<<<(N_NODES + 255) / 256, 256, 0, stream>>>(flags, N_NODES);
    mark_needed_kernel<<<(BATCH + 255) / 256, 256, 0, stream>>>(node_indices, flags);
    long long tot = (long long)N_EDGES * 64;
    scatter_edges_kernel<<<(int)((tot + 255) / 256), 256, 0, stream>>>(
        cache, edge_index, edge_weight, flags, agg);
  }

  // 2) graph tail GEMMs (fp32)
  launch_gemm_f32<2, 1, 0>(cache, w_root,  nullptr, nullptr, tmp,  N_NODES, GNN_D, GNN_D, stream);
  launch_gemm_f32<2, 1, 1>(agg,   w_neigh, nullptr, tmp,     tmp,  N_NODES, GNN_D, GNN_D, stream);
  launch_gemm_f32<2, 1, 0>(tmp,   w_post,  b_post,  nullptr, nemb, N_NODES, GNN_D, GNN_D, stream);

  // 3) gather + input LN (bf16 out), input proj (MFMA) -> h fp32
  gather_ln_kernel<<<BATCH, 256, 0, stream>>>(nemb, fallback, node_indices,
                                              ln_in_scale, ln_in_bias, pertln);
  launch_mfma<0, 0, 0>(pertln, w_in_bf, nullptr, h, BATCH, H_D, GNN_D, stream);

  // 4) residual blocks: LN -> fc1(gelu, bf16 out) -> fc2(+h, fp32 out)
  for (int i = 0; i < L_N; ++i) {
    ln512_kernel<<<BATCH, 256, 0, stream>>>(h, rb_ln_scale + (size_t)i * H_D,
                                            rb_ln_bias + (size_t)i * H_D, yln);
    launch_mfma<2, 1, 0>(yln,  fc1_bf + (size_t)i * MID_D * H_D, nullptr, ymid,
                         BATCH, MID_D, H_D, stream);
    launch_mfma<0, 0, 1>(ymid, fc2_bf + (size_t)i * H_D * MID_D, h, h,
                         BATCH, H_D, MID_D, stream);
  }

  // 5) bilinear head (bf16) + gene einsum (fp32 out, N masked)
  {
    int n4 = BATCH * H_D / 4;
    f32_to_bf16_kernel<<<(n4 + 255) / 256, 256, 0, stream>>>(h, h_bf, n4);
  }
  launch_mfma<0, 1, 0>(h_bf, wbil_bf, nullptr, blin, BATCH, C_N * R_D, H_D, stream);
  launch_mfma<0, 0, 0>(blin, gene_bf, nullptr, out, BATCH * C_N, G_N, R_D, stream);
}

// Round 3
// 857.823 us; speedup vs baseline: 6.0109x; 1.5250x over previous
//
#include <hip/hip_runtime.h>
#include <hip/hip_bf16.h>

#define N_NODES 19000
#define N_EDGES 600000
#define BATCH   4096
#define GNN_D   256
#define H_D     512
#define MID_D   2048
#define L_N     6
#define C_N     3
#define R_D     512
#define G_N     6640
#define LN_EPS  1e-5f
#define MAXDEG  128

typedef __attribute__((ext_vector_type(8))) short short8;
typedef __attribute__((ext_vector_type(4))) float f32x4;
typedef __hip_bfloat16 bf16;

// ---------------- small utility kernels ----------------

__global__ void f32_to_bf16_kernel(const float* __restrict__ in, bf16* __restrict__ out, int n4) {
  int i = blockIdx.x * blockDim.x + threadIdx.x;
  if (i >= n4) return;
  float4 v = ((const float4*)in)[i];
  out[i * 4 + 0] = __float2bfloat16(v.x);
  out[i * 4 + 1] = __float2bfloat16(v.y);
  out[i * 4 + 2] = __float2bfloat16(v.z);
  out[i * 4 + 3] = __float2bfloat16(v.w);
}

__global__ void init_meta_kernel(int* __restrict__ flags, int* __restrict__ cursor,
                                 int* __restrict__ nuniq) {
  int i = blockIdx.x * blockDim.x + threadIdx.x;
  if (i < N_NODES) flags[i] = 0;
  if (i < BATCH) cursor[i] = 0;
  if (i == 0) *nuniq = 0;
}

__global__ void mark_needed_kernel(const int* __restrict__ idx, int* __restrict__ flags) {
  int i = blockIdx.x * blockDim.x + threadIdx.x;
  if (i < BATCH) {
    int id = idx[i];
    if (id >= 0) flags[id] = 1;
  }
}

__global__ void assign_slots_kernel(const int* __restrict__ flags, int* __restrict__ slot,
                                    int* __restrict__ uniq, int* __restrict__ nuniq) {
  int i = blockIdx.x * blockDim.x + threadIdx.x;
  if (i >= N_NODES) return;
  if (flags[i]) {
    int s = atomicAdd(nuniq, 1);
    slot[i] = s;
    uniq[s] = i;
  }
}

// one thread per edge: append (src, w) into dst-slot bucket
__global__ __launch_bounds__(256) void fill_edges_kernel(
    const int* __restrict__ ei, const float* __restrict__ ew,
    const int* __restrict__ flags, const int* __restrict__ slot,
    int* __restrict__ cursor, int* __restrict__ el_src, float* __restrict__ el_w) {
  int e = blockIdx.x * blockDim.x + threadIdx.x;
  if (e >= N_EDGES) return;
  int dst = ei[N_EDGES + e];
  if (!flags[dst]) return;
  int s = slot[dst];
  int p = atomicAdd(&cursor[s], 1);
  if (p < MAXDEG) {
    el_src[s * MAXDEG + p] = ei[e];
    el_w[s * MAXDEG + p] = ew[e];
  }
}

// one block per slot: aggc[s] = sum_e w_e * cache[src_e]; cachec[s] = cache[uniq[s]]
__global__ __launch_bounds__(256) void gather_nodes_kernel(
    const float* __restrict__ cache, const int* __restrict__ uniq,
    const int* __restrict__ cursor, const int* __restrict__ nuniq,
    const int* __restrict__ el_src, const float* __restrict__ el_w,
    float* __restrict__ aggc, float* __restrict__ cachec) {
  int s = blockIdx.x, t = threadIdx.x;
  if (s >= *nuniq) {
    aggc[(size_t)s * GNN_D + t] = 0.f;
    cachec[(size_t)s * GNN_D + t] = 0.f;
    return;
  }
  cachec[(size_t)s * GNN_D + t] = cache[(size_t)uniq[s] * GNN_D + t];
  int deg = cursor[s];
  deg = (deg < MAXDEG) ? deg : MAXDEG;
  float acc = 0.f;
  for (int e = 0; e < deg; ++e) {
    int src = el_src[s * MAXDEG + e];
    float w = el_w[s * MAXDEG + e];
    acc += cache[(size_t)src * GNN_D + t] * w;
  }
  aggc[(size_t)s * GNN_D + t] = acc;
}

// gather (with -1 fallback) + LayerNorm over 256 -> bf16 ; reads compact emb
__global__ __launch_bounds__(256) void gather_ln_kernel(
    const float* __restrict__ embc, const int* __restrict__ slot,
    const float* __restrict__ fallback, const int* __restrict__ idx,
    const float* __restrict__ scale, const float* __restrict__ bias,
    bf16* __restrict__ out) {
  int b = blockIdx.x, t = threadIdx.x;
  int id = idx[b];
  float v = (id >= 0) ? embc[(size_t)slot[id] * GNN_D + t] : fallback[t];
  float s = v, q = v * v;
#pragma unroll
  for (int o = 32; o > 0; o >>= 1) { s += __shfl_down(s, o); q += __shfl_down(q, o); }
  __shared__ float ls[4], lq[4];
  int wv = t >> 6, ln = t & 63;
  if (ln == 0) { ls[wv] = s; lq[wv] = q; }
  __syncthreads();
  s = ls[0] + ls[1] + ls[2] + ls[3];
  q = lq[0] + lq[1] + lq[2] + lq[3];
  float mu = s * (1.f / GNN_D);
  float var = q * (1.f / GNN_D) - mu * mu;
  float r = rsqrtf(var + LN_EPS);
  out[(size_t)b * GNN_D + t] = __float2bfloat16((v - mu) * r * scale[t] + bias[t]);
}

// LayerNorm over 512 -> bf16
__global__ __launch_bounds__(256) void ln512_kernel(
    const float* __restrict__ x, const float* __restrict__ scale,
    const float* __restrict__ bias, bf16* __restrict__ out) {
  int b = blockIdx.x, t = threadIdx.x;
  const float* xr = x + (size_t)b * H_D;
  float v0 = xr[t];
  float v1 = xr[256 + t];
  float s = v0 + v1, q = v0 * v0 + v1 * v1;
#pragma unroll
  for (int o = 32; o > 0; o >>= 1) { s += __shfl_down(s, o); q += __shfl_down(q, o); }
  __shared__ float ls[4], lq[4];
  int wv = t >> 6, ln = t & 63;
  if (ln == 0) { ls[wv] = s; lq[wv] = q; }
  __syncthreads();
  s = ls[0] + ls[1] + ls[2] + ls[3];
  q = lq[0] + lq[1] + lq[2] + lq[3];
  float mu = s * (1.f / H_D);
  float var = q * (1.f / H_D) - mu * mu;
  float r = rsqrtf(var + LN_EPS);
  bf16* orow = out + (size_t)b * H_D;
  orow[t]       = __float2bfloat16((v0 - mu) * r * scale[t]       + bias[t]);
  orow[256 + t] = __float2bfloat16((v1 - mu) * r * scale[256 + t] + bias[256 + t]);
}

__device__ inline float gelu_exact(float x) {
  return 0.5f * x * (1.f + erff(x * 0.70710678118654752f));
}

// ---------------- fp32 tiled GEMM (compact graph tail) ----------------

template <int NQR, int NQC, int ACT>  // ACT: 0 none, 1 relu
__global__ __launch_bounds__(256) void gemm_f32_kernel(
    const float* __restrict__ A, const float* __restrict__ W,
    const float* __restrict__ bias, const float* __restrict__ addC,
    float* __restrict__ C, int M, int N, int K) {
  constexpr int BM = NQR * 64;
  constexpr int BN = NQC * 64;
  __shared__ __align__(16) float sA[16][BM];
  __shared__ __align__(16) float sB[16][BN];

  const int tid = threadIdx.x;
  const int tx = tid & 15, ty = tid >> 4;
  const int bm = blockIdx.x * BM;
  const int bn = blockIdx.y * BN;

  float acc[NQR * 4][NQC * 4];
#pragma unroll
  for (int i = 0; i < NQR * 4; ++i)
#pragma unroll
    for (int j = 0; j < NQC * 4; ++j) acc[i][j] = 0.f;

  for (int k0 = 0; k0 < K; k0 += 16) {
#pragma unroll
    for (int q = 0; q < NQR; ++q) {
      int li = tid + q * 256;
      int row = li >> 2;
      int kq = (li & 3) << 2;
      int ar = min(bm + row, M - 1);
      float4 av = *(const float4*)(A + (size_t)ar * K + k0 + kq);
      sA[kq + 0][row] = av.x; sA[kq + 1][row] = av.y;
      sA[kq + 2][row] = av.z; sA[kq + 3][row] = av.w;
    }
#pragma unroll
    for (int q = 0; q < NQC; ++q) {
      int li = tid + q * 256;
      int row = li >> 2;
      int kq = (li & 3) << 2;
      int wr = min(bn + row, N - 1);
      float4 wv = *(const float4*)(W + (size_t)wr * K + k0 + kq);
      sB[kq + 0][row] = wv.x; sB[kq + 1][row] = wv.y;
      sB[kq + 2][row] = wv.z; sB[kq + 3][row] = wv.w;
    }
    __syncthreads();
#pragma unroll
    for (int kk = 0; kk < 16; ++kk) {
      float4 av[NQR], bv[NQC];
#pragma unroll
      for (int q = 0; q < NQR; ++q) av[q] = *(const float4*)&sA[kk][q * 64 + ty * 4];
#pragma unroll
      for (int q = 0; q < NQC; ++q) bv[q] = *(const float4*)&sB[kk][q * 64 + tx * 4];
      const float* ap = (const float*)av;
      const float* bp = (const float*)bv;
#pragma unroll
      for (int i = 0; i < NQR * 4; ++i)
#pragma unroll
        for (int j = 0; j < NQC * 4; ++j) acc[i][j] += ap[i] * bp[j];
    }
    __syncthreads();
  }

#pragma unroll
  for (int qr = 0; qr < NQR; ++qr) {
#pragma unroll
    for (int i = 0; i < 4; ++i) {
      int row = bm + qr * 64 + ty * 4 + i;
      if (row >= M) continue;
#pragma unroll
      for (int qc = 0; qc < NQC; ++qc) {
        int col = bn + qc * 64 + tx * 4;
        if (col >= N) continue;
        float4 v = make_float4(acc[qr * 4 + i][qc * 4 + 0], acc[qr * 4 + i][qc * 4 + 1],
                               acc[qr * 4 + i][qc * 4 + 2], acc[qr * 4 + i][qc * 4 + 3]);
        if (bias) {
          v.x += bias[col]; v.y += bias[col + 1]; v.z += bias[col + 2]; v.w += bias[col + 3];
        }
        if (addC) {
          float4 ad = *(const float4*)(addC + (size_t)row * N + col);
          v.x += ad.x; v.y += ad.y; v.z += ad.z; v.w += ad.w;
        }
        if (ACT == 1) {
          v.x = fmaxf(v.x, 0.f); v.y = fmaxf(v.y, 0.f);
          v.z = fmaxf(v.z, 0.f); v.w = fmaxf(v.w, 0.f);
        }
        *(float4*)(C + (size_t)row * N + col) = v;
      }
    }
  }
}

template <int NQR, int NQC, int ACT>
static void launch_gemm_f32(const float* A, const float* W, const float* bias,
                            const float* addC, float* C, int M, int N, int K,
                            hipStream_t stream) {
  dim3 grid((M + NQR * 64 - 1) / (NQR * 64), (N + NQC * 64 - 1) / (NQC * 64));
  gemm_f32_kernel<NQR, NQC, ACT><<<grid, 256, 0, stream>>>(A, W, bias, addC, C, M, N, K);
}

// ---------------- bf16 MFMA GEMM: C = act(A @ W^T [+ addC]) ----------------
// 128x128 tile, BK=32, 4 waves each owning 64x64 (4x4 frags of 16x16x32).

template <int ACT, int OUT_BF16, int ADDC>  // ACT: 0 none, 2 gelu
__global__ __launch_bounds__(256) void gemm_mfma_kernel(
    const bf16* __restrict__ A, const bf16* __restrict__ W,
    const float* __restrict__ addC, void* __restrict__ Cout,
    int M, int N, int K) {
  __shared__ __align__(16) bf16 sA[128 * 32];
  __shared__ __align__(16) bf16 sB[128 * 32];
  const int tid = threadIdx.x;
  const int lane = tid & 63;
  const int wid = tid >> 6;
  const int wr = wid >> 1, wc = wid & 1;
  const int bm = blockIdx.x * 128, bn = blockIdx.y * 128;

  f32x4 acc[4][4];
#pragma unroll
  for (int m = 0; m < 4; ++m)
#pragma unroll
    for (int n = 0; n < 4; ++n) acc[m][n] = (f32x4){0.f, 0.f, 0.f, 0.f};

  const int rbase = lane & 15;
  const int g = lane >> 4;

  for (int k0 = 0; k0 < K; k0 += 32) {
#pragma unroll
    for (int i = 0; i < 2; ++i) {
      int li = i * 256 + tid;
      int row = li >> 2;
      int kq = (li & 3) << 3;
      int ar = bm + row; ar = (ar < M) ? ar : (M - 1);
      int br = bn + row; br = (br < N) ? br : (N - 1);
      __builtin_amdgcn_global_load_lds(
          (const __attribute__((address_space(1))) void*)(A + (size_t)ar * K + k0 + kq),
          (__attribute__((address_space(3))) void*)(sA + li * 8), 16, 0, 0);
      __builtin_amdgcn_global_load_lds(
          (const __attribute__((address_space(1))) void*)(W + (size_t)br * K + k0 + kq),
          (__attribute__((address_space(3))) void*)(sB + li * 8), 16, 0, 0);
    }
    __syncthreads();

    short8 af[4], bfrag[4];
#pragma unroll
    for (int m = 0; m < 4; ++m)
      af[m] = *(const short8*)(sA + (wr * 64 + m * 16 + rbase) * 32 + g * 8);
#pragma unroll
    for (int n = 0; n < 4; ++n)
      bfrag[n] = *(const short8*)(sB + (wc * 64 + n * 16 + rbase) * 32 + g * 8);
#pragma unroll
    for (int m = 0; m < 4; ++m)
#pragma unroll
      for (int n = 0; n < 4; ++n)
        acc[m][n] = __builtin_amdgcn_mfma_f32_16x16x32_bf16(af[m], bfrag[n], acc[m][n], 0, 0, 0);
    __syncthreads();
  }

  const int rb = (lane >> 4) * 4;
  const int cb = lane & 15;
#pragma unroll
  for (int m = 0; m < 4; ++m) {
#pragma unroll
    for (int n = 0; n < 4; ++n) {
      int col = bn + wc * 64 + n * 16 + cb;
      if (col >= N) continue;
      int row0 = bm + wr * 64 + m * 16 + rb;
#pragma unroll
      for (int r = 0; r < 4; ++r) {
        int row = row0 + r;
        if (row >= M) continue;
        float v = acc[m][n][r];
        if (ADDC) v += addC[(size_t)row * N + col];
        if (ACT == 2) v = gelu_exact(v);
        if (OUT_BF16)
          ((bf16*)Cout)[(size_t)row * N + col] = __float2bfloat16(v);
        else
          ((float*)Cout)[(size_t)row * N + col] = v;
      }
    }
  }
}

template <int ACT, int OUT_BF16, int ADDC>
static void launch_mfma(const bf16* A, const bf16* W, const float* addC, void* C,
                        int M, int N, int K, hipStream_t stream) {
  dim3 grid(M / 128, (N + 127) / 128);
  gemm_mfma_kernel<ACT, OUT_BF16, ADDC><<<grid, 256, 0, stream>>>(A, W, addC, C, M, N, K);
}

// ---------------- launch ----------------

#define MB (1024u * 1024u)

extern "C" void kernel_launch(void* const* d_in, const int* in_sizes, int n_in,
                              void* d_out, int out_size, void* d_ws, size_t ws_size,
                              hipStream_t stream) {
  const int*   node_indices = (const int*)d_in[0];
  const int*   edge_index   = (const int*)d_in[1];
  const float* edge_weight  = (const float*)d_in[2];
  const float* cache        = (const float*)d_in[3];
  const float* w_root       = (const float*)d_in[4];
  const float* w_neigh      = (const float*)d_in[5];
  const float* w_post       = (const float*)d_in[6];
  const float* b_post       = (const float*)d_in[7];
  const float* fallback     = (const float*)d_in[8];
  const float* ln_in_scale  = (const float*)d_in[9];
  const float* ln_in_bias   = (const float*)d_in[10];
  const float* w_in         = (const float*)d_in[11];
  const float* rb_ln_scale  = (const float*)d_in[12];
  const float* rb_ln_bias   = (const float*)d_in[13];
  const float* rb_fc1       = (const float*)d_in[14];
  const float* rb_fc2       = (const float*)d_in[15];
  const float* w_bil        = (const float*)d_in[16];
  const float* gene         = (const float*)d_in[17];
  float* out = (float*)d_out;

  char* w = (char*)d_ws;
  // --- region A (0..24 MB): graph-stage buffers, dead after gather_ln; ymid aliases it ---
  float* aggc   = (float*)(w + 0 * MB);    // 4096*256*4 = 4 MB
  float* cachec = (float*)(w + 4 * MB);    // 4 MB
  float* tmpa   = (float*)(w + 8 * MB);    // 4 MB
  float* embc   = (float*)(w + 12 * MB);   // 4 MB
  int*   el_src = (int*)  (w + 16 * MB);   // 4096*128*4 = 2 MB
  float* el_w   = (float*)(w + 18 * MB);   // 2 MB
  int*   flags  = (int*)  (w + 20 * MB);            // 76 KB
  int*   slot   = (int*)  (w + 20 * MB + 80 * 1024); // 76 KB
  int*   uniq   = (int*)  (w + 20 * MB + 160 * 1024); // 16 KB
  int*   cursor = (int*)  (w + 20 * MB + 180 * 1024); // 16 KB
  int*   nuniq  = (int*)  (w + 20 * MB + 200 * 1024); // 4 B
  bf16*  ymid   = (bf16*) (w + 0 * MB);    // 4096*2048*2 = 16 MB (phase-4 only)
  // --- region B (24 MB..): activations + bf16 weights ---
  bf16*  pertln = (bf16*) (w + 24 * MB);   // 2 MB
  float* h      = (float*)(w + 26 * MB);   // 8 MB
  bf16*  yln    = (bf16*) (w + 34 * MB);   // 4 MB
  bf16*  h_bf   = (bf16*) (w + 38 * MB);   // 4 MB
  bf16*  blin   = (bf16*) (w + 42 * MB);   // 12 MB
  bf16*  w_in_bf = (bf16*)(w + 55 * MB);   // 256 KB
  bf16*  fc1_bf  = (bf16*)(w + 56 * MB);   // 12 MB
  bf16*  fc2_bf  = (bf16*)(w + 68 * MB);   // 12 MB
  bf16*  wbil_bf = (bf16*)(w + 80 * MB);   // 1.5 MB
  bf16*  gene_bf = (bf16*)(w + 82 * MB);   // 6.5 MB

  // 0) weight conversions to bf16
  {
    int n4;
    n4 = H_D * GNN_D / 4;
    f32_to_bf16_kernel<<<(n4 + 255) / 256, 256, 0, stream>>>(w_in, w_in_bf, n4);
    n4 = L_N * MID_D * H_D / 4;
    f32_to_bf16_kernel<<<(n4 + 255) / 256, 256, 0, stream>>>(rb_fc1, fc1_bf, n4);
    f32_to_bf16_kernel<<<(n4 + 255) / 256, 256, 0, stream>>>(rb_fc2, fc2_bf, n4);
    n4 = C_N * R_D * H_D / 4;
    f32_to_bf16_kernel<<<(n4 + 255) / 256, 256, 0, stream>>>(w_bil, wbil_bf, n4);
    n4 = G_N * R_D / 4;
    f32_to_bf16_kernel<<<(n4 + 255) / 256, 256, 0, stream>>>(gene, gene_bf, n4);
  }

  // 1) compact-slot construction + bucketed edge lists + gather-accumulate
  init_meta_kernel<<<(N_NODES + 255) / 256, 256, 0, stream>>>(flags, cursor, nuniq);
  mark_needed_kernel<<<(BATCH + 255) / 256, 256, 0, stream>>>(node_indices, flags);
  assign_slots_kernel<<<(N_NODES + 255) / 256, 256, 0, stream>>>(flags, slot, uniq, nuniq);
  fill_edges_kernel<<<(N_EDGES + 255) / 256, 256, 0, stream>>>(
      edge_index, edge_weight, flags, slot, cursor, el_src, el_w);
  gather_nodes_kernel<<<BATCH, 256, 0, stream>>>(
      cache, uniq, cursor, nuniq, el_src, el_w, aggc, cachec);

  // 2) compact graph tail GEMMs (fp32), M = 4096 slots
  launch_gemm_f32<1, 1, 0>(cachec, w_root,  nullptr, nullptr, tmpa, BATCH, GNN_D, GNN_D, stream);
  launch_gemm_f32<1, 1, 1>(aggc,   w_neigh, nullptr, tmpa,    tmpa, BATCH, GNN_D, GNN_D, stream);
  launch_gemm_f32<1, 1, 0>(tmpa,   w_post,  b_post,  nullptr, embc, BATCH, GNN_D, GNN_D, stream);

  // 3) gather + input LN (bf16 out), input proj (MFMA) -> h fp32
  gather_ln_kernel<<<BATCH, 256, 0, stream>>>(embc, slot, fallback, node_indices,
                                              ln_in_scale, ln_in_bias, pertln);
  launch_mfma<0, 0, 0>(pertln, w_in_bf, nullptr, h, BATCH, H_D, GNN_D, stream);

  // 4) residual blocks: LN -> fc1(gelu, bf16 out) -> fc2(+h, fp32 out)
  for (int i = 0; i < L_N; ++i) {
    ln512_kernel<<<BATCH, 256, 0, stream>>>(h, rb_ln_scale + (size_t)i * H_D,
                                            rb_ln_bias + (size_t)i * H_D, yln);
    launch_mfma<2, 1, 0>(yln,  fc1_bf + (size_t)i * MID_D * H_D, nullptr, ymid,
                         BATCH, MID_D, H_D, stream);
    launch_mfma<0, 0, 1>(ymid, fc2_bf + (size_t)i * H_D * MID_D, h, h,
                         BATCH, H_D, MID_D, stream);
  }

  // 5) bilinear head (bf16) + gene einsum (fp32 out, N masked)
  {
    int n4 = BATCH * H_D / 4;
    f32_to_bf16_kernel<<<(n4 + 255) / 256, 256, 0, stream>>>(h, h_bf, n4);
  }
  launch_mfma<0, 1, 0>(h_bf, wbil_bf, nullptr, blin, BATCH, C_N * R_D, H_D, stream);
  launch_mfma<0, 0, 0>(blin, gene_bf, nullptr, out, BATCH * C_N, G_N, R_D, stream);
}

// Round 4
// 732.090 us; speedup vs baseline: 7.0433x; 1.1717x over previous
//
#include <hip/hip_runtime.h>
#include <hip/hip_bf16.h>

#define N_NODES 19000
#define N_EDGES 600000
#define BATCH   4096
#define GNN_D   256
#define H_D     512
#define MID_D   2048
#define L_N     6
#define C_N     3
#define R_D     512
#define G_N     6640
#define LN_EPS  1e-5f
#define MAXDEG  128

typedef __attribute__((ext_vector_type(8))) short short8;
typedef __attribute__((ext_vector_type(4))) float f32x4;
typedef __hip_bfloat16 bf16;

// ---------------- small utility kernels ----------------

__global__ void f32_to_bf16_kernel(const float* __restrict__ in, bf16* __restrict__ out, int n4) {
  int i = blockIdx.x * blockDim.x + threadIdx.x;
  if (i >= n4) return;
  float4 v = ((const float4*)in)[i];
  out[i * 4 + 0] = __float2bfloat16(v.x);
  out[i * 4 + 1] = __float2bfloat16(v.y);
  out[i * 4 + 2] = __float2bfloat16(v.z);
  out[i * 4 + 3] = __float2bfloat16(v.w);
}

// combined [w_root | w_neigh] -> bf16 [GNN_D x 2*GNN_D]
__global__ void build_wrn_kernel(const float* __restrict__ w_root,
                                 const float* __restrict__ w_neigh,
                                 bf16* __restrict__ out) {
  int i4 = blockIdx.x * blockDim.x + threadIdx.x;           // over 256*512/4
  if (i4 >= GNN_D * 2 * GNN_D / 4) return;
  int base = i4 * 4;
  int n = base >> 9;          // row (out of 256)
  int k = base & 511;         // col (out of 512)
  const float* src = (k < GNN_D) ? (w_root + (size_t)n * GNN_D + k)
                                 : (w_neigh + (size_t)n * GNN_D + (k - GNN_D));
  float4 v = *(const float4*)src;
  out[base + 0] = __float2bfloat16(v.x);
  out[base + 1] = __float2bfloat16(v.y);
  out[base + 2] = __float2bfloat16(v.z);
  out[base + 3] = __float2bfloat16(v.w);
}

__global__ void init_meta_kernel(int* __restrict__ flags, int* __restrict__ cursor,
                                 int* __restrict__ nuniq) {
  int i = blockIdx.x * blockDim.x + threadIdx.x;
  if (i < N_NODES) flags[i] = 0;
  if (i < BATCH) cursor[i] = 0;
  if (i == 0) *nuniq = 0;
}

__global__ void mark_needed_kernel(const int* __restrict__ idx, int* __restrict__ flags) {
  int i = blockIdx.x * blockDim.x + threadIdx.x;
  if (i < BATCH) {
    int id = idx[i];
    if (id >= 0) flags[id] = 1;
  }
}

__global__ void assign_slots_kernel(const int* __restrict__ flags, int* __restrict__ slot,
                                    int* __restrict__ uniq, int* __restrict__ nuniq) {
  int i = blockIdx.x * blockDim.x + threadIdx.x;
  if (i >= N_NODES) return;
  if (flags[i]) {
    int s = atomicAdd(nuniq, 1);
    slot[i] = s;
    uniq[s] = i;
  }
}

// one thread per edge: append (src, w) into dst-slot bucket
__global__ __launch_bounds__(256) void fill_edges_kernel(
    const int* __restrict__ ei, const float* __restrict__ ew,
    const int* __restrict__ flags, const int* __restrict__ slot,
    int* __restrict__ cursor, int* __restrict__ el_src, float* __restrict__ el_w) {
  int e = blockIdx.x * blockDim.x + threadIdx.x;
  if (e >= N_EDGES) return;
  int dst = ei[N_EDGES + e];
  if (!flags[dst]) return;
  int s = slot[dst];
  int p = atomicAdd(&cursor[s], 1);
  if (p < MAXDEG) {
    el_src[s * MAXDEG + p] = ei[e];
    el_w[s * MAXDEG + p] = ew[e];
  }
}

// one block per slot: compact2[s] = [ cache[uniq[s]] | sum_e w_e*cache[src_e] ]  (bf16)
__global__ __launch_bounds__(256) void gather_nodes_kernel(
    const float* __restrict__ cache, const int* __restrict__ uniq,
    const int* __restrict__ cursor, const int* __restrict__ nuniq,
    const int* __restrict__ el_src, const float* __restrict__ el_w,
    bf16* __restrict__ compact2) {
  int s = blockIdx.x, t = threadIdx.x;
  bf16* row = compact2 + (size_t)s * (2 * GNN_D);
  if (s >= *nuniq) {
    row[t] = __float2bfloat16(0.f);
    row[GNN_D + t] = __float2bfloat16(0.f);
    return;
  }
  row[t] = __float2bfloat16(cache[(size_t)uniq[s] * GNN_D + t]);
  int deg = cursor[s];
  deg = (deg < MAXDEG) ? deg : MAXDEG;
  float acc = 0.f;
  for (int e = 0; e < deg; ++e) {
    int src = el_src[s * MAXDEG + e];
    float w = el_w[s * MAXDEG + e];
    acc += cache[(size_t)src * GNN_D + t] * w;
  }
  row[GNN_D + t] = __float2bfloat16(acc);
}

// gather (with -1 fallback) + LayerNorm over 256 -> bf16 ; reads compact emb (fp32)
__global__ __launch_bounds__(256) void gather_ln_kernel(
    const float* __restrict__ embc, const int* __restrict__ slot,
    const float* __restrict__ fallback, const int* __restrict__ idx,
    const float* __restrict__ scale, const float* __restrict__ bias,
    bf16* __restrict__ out) {
  int b = blockIdx.x, t = threadIdx.x;
  int id = idx[b];
  float v = (id >= 0) ? embc[(size_t)slot[id] * GNN_D + t] : fallback[t];
  float s = v, q = v * v;
#pragma unroll
  for (int o = 32; o > 0; o >>= 1) { s += __shfl_down(s, o); q += __shfl_down(q, o); }
  __shared__ float ls[4], lq[4];
  int wv = t >> 6, ln = t & 63;
  if (ln == 0) { ls[wv] = s; lq[wv] = q; }
  __syncthreads();
  s = ls[0] + ls[1] + ls[2] + ls[3];
  q = lq[0] + lq[1] + lq[2] + lq[3];
  float mu = s * (1.f / GNN_D);
  float var = q * (1.f / GNN_D) - mu * mu;
  float r = rsqrtf(var + LN_EPS);
  out[(size_t)b * GNN_D + t] = __float2bfloat16((v - mu) * r * scale[t] + bias[t]);
}

// LayerNorm over 512 -> bf16
__global__ __launch_bounds__(256) void ln512_kernel(
    const float* __restrict__ x, const float* __restrict__ scale,
    const float* __restrict__ bias, bf16* __restrict__ out) {
  int b = blockIdx.x, t = threadIdx.x;
  const float* xr = x + (size_t)b * H_D;
  float v0 = xr[t];
  float v1 = xr[256 + t];
  float s = v0 + v1, q = v0 * v0 + v1 * v1;
#pragma unroll
  for (int o = 32; o > 0; o >>= 1) { s += __shfl_down(s, o); q += __shfl_down(q, o); }
  __shared__ float ls[4], lq[4];
  int wv = t >> 6, ln = t & 63;
  if (ln == 0) { ls[wv] = s; lq[wv] = q; }
  __syncthreads();
  s = ls[0] + ls[1] + ls[2] + ls[3];
  q = lq[0] + lq[1] + lq[2] + lq[3];
  float mu = s * (1.f / H_D);
  float var = q * (1.f / H_D) - mu * mu;
  float r = rsqrtf(var + LN_EPS);
  bf16* orow = out + (size_t)b * H_D;
  orow[t]       = __float2bfloat16((v0 - mu) * r * scale[t]       + bias[t]);
  orow[256 + t] = __float2bfloat16((v1 - mu) * r * scale[256 + t] + bias[256 + t]);
}

__device__ inline float gelu_exact(float x) {
  return 0.5f * x * (1.f + erff(x * 0.70710678118654752f));
}

// ---------------- bf16 MFMA GEMM: C = act(A @ W^T [+ bias] [+ addC]) ----------------
// A: [M,K] bf16 row-major, W: [N,K] bf16 row-major. M % 128 == 0, K % 32 == 0.
// BM=128, BN=NBN*64. 4 waves (2x2): each wave owns 64 x (NBN*32).
// ACT: 0 none, 1 relu, 2 gelu. HBF: also write bf16 copy to out2. SWZ: XCD swizzle (1D grid).

template <int NBN, int ACT, int OUT_BF16, int ADDC, int BIAS, int HBF, int SWZ>
__global__ __launch_bounds__(256) void gemm_mfma_kernel(
    const bf16* __restrict__ A, const bf16* __restrict__ W,
    const float* __restrict__ bias, const float* __restrict__ addC,
    void* __restrict__ Cout, bf16* __restrict__ out2,
    int M, int N, int K, int gx) {
  constexpr int BN = NBN * 64;
  constexpr int NF_N = NBN * 2;    // 16-wide n-fragments per wave
  __shared__ __align__(16) bf16 sA[128 * 32];
  __shared__ __align__(16) bf16 sB[BN * 32];
  const int tid = threadIdx.x;
  const int lane = tid & 63;
  const int wid = tid >> 6;
  const int wr = wid >> 1, wc = wid & 1;

  int bidx, bidy;
  if (SWZ) {
    int nwg = gridDim.x;
    int bid = blockIdx.x;
    int q = nwg >> 3, r = nwg & 7;
    int xcd = bid & 7, orig = bid >> 3;
    int swz = (xcd < r ? xcd * (q + 1) : r * (q + 1) + (xcd - r) * q) + orig;
    bidx = swz % gx;
    bidy = swz / gx;
  } else {
    bidx = blockIdx.x;
    bidy = blockIdx.y;
  }
  const int bm = bidx * 128, bn = bidy * BN;

  f32x4 acc[4][NF_N];
#pragma unroll
  for (int m = 0; m < 4; ++m)
#pragma unroll
    for (int n = 0; n < NF_N; ++n) acc[m][n] = (f32x4){0.f, 0.f, 0.f, 0.f};

  const int rbase = lane & 15;
  const int g = lane >> 4;

  for (int k0 = 0; k0 < K; k0 += 32) {
#pragma unroll
    for (int i = 0; i < 2; ++i) {
      int li = i * 256 + tid;
      int row = li >> 2;
      int kq = (li & 3) << 3;
      int ar = bm + row; ar = (ar < M) ? ar : (M - 1);
      __builtin_amdgcn_global_load_lds(
          (const __attribute__((address_space(1))) void*)(A + (size_t)ar * K + k0 + kq),
          (__attribute__((address_space(3))) void*)(sA + li * 8), 16, 0, 0);
    }
#pragma unroll
    for (int i = 0; i < NBN; ++i) {
      int li = i * 256 + tid;
      int row = li >> 2;
      int kq = (li & 3) << 3;
      int br = bn + row; br = (br < N) ? br : (N - 1);
      __builtin_amdgcn_global_load_lds(
          (const __attribute__((address_space(1))) void*)(W + (size_t)br * K + k0 + kq),
          (__attribute__((address_space(3))) void*)(sB + li * 8), 16, 0, 0);
    }
    __syncthreads();

    short8 af[4], bfrag[NF_N];
#pragma unroll
    for (int m = 0; m < 4; ++m)
      af[m] = *(const short8*)(sA + (wr * 64 + m * 16 + rbase) * 32 + g * 8);
#pragma unroll
    for (int n = 0; n < NF_N; ++n)
      bfrag[n] = *(const short8*)(sB + (wc * (NBN * 32) + n * 16 + rbase) * 32 + g * 8);
#pragma unroll
    for (int m = 0; m < 4; ++m)
#pragma unroll
      for (int n = 0; n < NF_N; ++n)
        acc[m][n] = __builtin_amdgcn_mfma_f32_16x16x32_bf16(af[m], bfrag[n], acc[m][n], 0, 0, 0);
    __syncthreads();
  }

  // C/D frag mapping: col = lane&15, row = (lane>>4)*4 + reg   [m89-verified]
  const int rb = (lane >> 4) * 4;
  const int cb = lane & 15;
#pragma unroll
  for (int m = 0; m < 4; ++m) {
#pragma unroll
    for (int n = 0; n < NF_N; ++n) {
      int col = bn + wc * (NBN * 32) + n * 16 + cb;
      if (col >= N) continue;
      int row0 = bm + wr * 64 + m * 16 + rb;
#pragma unroll
      for (int r = 0; r < 4; ++r) {
        int row = row0 + r;
        if (row >= M) continue;
        float v = acc[m][n][r];
        if (BIAS) v += bias[col];
        if (ADDC) v += addC[(size_t)row * N + col];
        if (ACT == 1) v = fmaxf(v, 0.f);
        if (ACT == 2) v = gelu_exact(v);
        if (OUT_BF16)
          ((bf16*)Cout)[(size_t)row * N + col] = __float2bfloat16(v);
        else
          ((float*)Cout)[(size_t)row * N + col] = v;
        if (HBF)
          out2[(size_t)row * N + col] = __float2bfloat16(v);
      }
    }
  }
}

template <int NBN, int ACT, int OUT_BF16, int ADDC, int BIAS, int HBF>
static void launch_mfma(const bf16* A, const bf16* W, const float* bias,
                        const float* addC, void* C, bf16* out2,
                        int M, int N, int K, hipStream_t stream) {
  dim3 grid(M / 128, (N + NBN * 64 - 1) / (NBN * 64));
  gemm_mfma_kernel<NBN, ACT, OUT_BF16, ADDC, BIAS, HBF, 0>
      <<<grid, 256, 0, stream>>>(A, W, bias, addC, C, out2, M, N, K, 0);
}

// ---------------- launch ----------------

#define MB (1024u * 1024u)

extern "C" void kernel_launch(void* const* d_in, const int* in_sizes, int n_in,
                              void* d_out, int out_size, void* d_ws, size_t ws_size,
                              hipStream_t stream) {
  const int*   node_indices = (const int*)d_in[0];
  const int*   edge_index   = (const int*)d_in[1];
  const float* edge_weight  = (const float*)d_in[2];
  const float* cache        = (const float*)d_in[3];
  const float* w_root       = (const float*)d_in[4];
  const float* w_neigh      = (const float*)d_in[5];
  const float* w_post       = (const float*)d_in[6];
  const float* b_post       = (const float*)d_in[7];
  const float* fallback     = (const float*)d_in[8];
  const float* ln_in_scale  = (const float*)d_in[9];
  const float* ln_in_bias   = (const float*)d_in[10];
  const float* w_in         = (const float*)d_in[11];
  const float* rb_ln_scale  = (const float*)d_in[12];
  const float* rb_ln_bias   = (const float*)d_in[13];
  const float* rb_fc1       = (const float*)d_in[14];
  const float* rb_fc2       = (const float*)d_in[15];
  const float* w_bil        = (const float*)d_in[16];
  const float* gene         = (const float*)d_in[17];
  float* out = (float*)d_out;

  char* w = (char*)d_ws;
  // --- region A (0..16 MB): graph-stage buffers, dead after gather_ln; ymid aliases ---
  bf16*  compact2 = (bf16*)(w + 0 * MB);   // 4096*512*2 = 4 MB
  bf16*  tmpc     = (bf16*)(w + 4 * MB);   // 4096*256*2 = 2 MB
  float* embc     = (float*)(w + 6 * MB);  // 4096*256*4 = 4 MB
  int*   el_src   = (int*)  (w + 10 * MB); // 2 MB
  float* el_w     = (float*)(w + 12 * MB); // 2 MB
  int*   flags    = (int*)  (w + 14 * MB);               // 76 KB
  int*   slot     = (int*)  (w + 14 * MB + 80 * 1024);   // 76 KB
  int*   uniq     = (int*)  (w + 14 * MB + 160 * 1024);  // 16 KB
  int*   cursor   = (int*)  (w + 14 * MB + 180 * 1024);  // 16 KB
  int*   nuniq    = (int*)  (w + 14 * MB + 200 * 1024);  // 4 B
  bf16*  ymid     = (bf16*) (w + 0 * MB);  // 16 MB (phase-4 only, after region A dead)
  // --- region B (24 MB..): activations + bf16 weights ---
  bf16*  pertln  = (bf16*) (w + 24 * MB);  // 2 MB
  float* h       = (float*)(w + 26 * MB);  // 8 MB
  bf16*  yln     = (bf16*) (w + 34 * MB);  // 4 MB
  bf16*  h_bf    = (bf16*) (w + 38 * MB);  // 4 MB
  bf16*  blin    = (bf16*) (w + 42 * MB);  // 12 MB
  bf16*  w_in_bf = (bf16*) (w + 55 * MB);  // 256 KB
  bf16*  fc1_bf  = (bf16*) (w + 56 * MB);  // 12 MB
  bf16*  fc2_bf  = (bf16*) (w + 68 * MB);  // 12 MB
  bf16*  wbil_bf = (bf16*) (w + 80 * MB);  // 1.5 MB
  bf16*  gene_bf = (bf16*) (w + 82 * MB);  // 6.8 MB
  bf16*  wrn_bf  = (bf16*) (w + 90 * MB);  // 256 KB
  bf16*  wpost_bf= (bf16*) (w + 91 * MB);  // 128 KB

  // 0) weight conversions to bf16
  {
    int n4;
    n4 = H_D * GNN_D / 4;
    f32_to_bf16_kernel<<<(n4 + 255) / 256, 256, 0, stream>>>(w_in, w_in_bf, n4);
    n4 = L_N * MID_D * H_D / 4;
    f32_to_bf16_kernel<<<(n4 + 255) / 256, 256, 0, stream>>>(rb_fc1, fc1_bf, n4);
    f32_to_bf16_kernel<<<(n4 + 255) / 256, 256, 0, stream>>>(rb_fc2, fc2_bf, n4);
    n4 = C_N * R_D * H_D / 4;
    f32_to_bf16_kernel<<<(n4 + 255) / 256, 256, 0, stream>>>(w_bil, wbil_bf, n4);
    n4 = G_N * R_D / 4;
    f32_to_bf16_kernel<<<(n4 + 255) / 256, 256, 0, stream>>>(gene, gene_bf, n4);
    n4 = GNN_D * GNN_D / 4;
    f32_to_bf16_kernel<<<(n4 + 255) / 256, 256, 0, stream>>>(w_post, wpost_bf, n4);
    int nw = GNN_D * 2 * GNN_D / 4;
    build_wrn_kernel<<<(nw + 255) / 256, 256, 0, stream>>>(w_root, w_neigh, wrn_bf);
  }

  // 1) compact-slot construction + bucketed edge lists + gather-accumulate (bf16 out)
  init_meta_kernel<<<(N_NODES + 255) / 256, 256, 0, stream>>>(flags, cursor, nuniq);
  mark_needed_kernel<<<(BATCH + 255) / 256, 256, 0, stream>>>(node_indices, flags);
  assign_slots_kernel<<<(N_NODES + 255) / 256, 256, 0, stream>>>(flags, slot, uniq, nuniq);
  fill_edges_kernel<<<(N_EDGES + 255) / 256, 256, 0, stream>>>(
      edge_index, edge_weight, flags, slot, cursor, el_src, el_w);
  gather_nodes_kernel<<<BATCH, 256, 0, stream>>>(
      cache, uniq, cursor, nuniq, el_src, el_w, compact2);

  // 2) compact graph tail (bf16 MFMA): relu([cache|agg] @ [w_root|w_neigh]^T) @ w_post^T + b
  launch_mfma<1, 1, 1, 0, 0, 0>(compact2, wrn_bf, nullptr, nullptr, tmpc, nullptr,
                                BATCH, GNN_D, 2 * GNN_D, stream);
  launch_mfma<1, 0, 0, 0, 1, 0>(tmpc, wpost_bf, b_post, nullptr, embc, nullptr,
                                BATCH, GNN_D, GNN_D, stream);

  // 3) gather + input LN (bf16 out), input proj (MFMA, BN=64) -> h fp32
  gather_ln_kernel<<<BATCH, 256, 0, stream>>>(embc, slot, fallback, node_indices,
                                              ln_in_scale, ln_in_bias, pertln);
  launch_mfma<1, 0, 0, 0, 0, 0>(pertln, w_in_bf, nullptr, nullptr, h, nullptr,
                                BATCH, H_D, GNN_D, stream);

  // 4) residual blocks: LN -> fc1(gelu, bf16, BN=128) -> fc2(+h, fp32, BN=64)
  for (int i = 0; i < L_N; ++i) {
    ln512_kernel<<<BATCH, 256, 0, stream>>>(h, rb_ln_scale + (size_t)i * H_D,
                                            rb_ln_bias + (size_t)i * H_D, yln);
    launch_mfma<2, 2, 1, 0, 0, 0>(yln, fc1_bf + (size_t)i * MID_D * H_D, nullptr, nullptr,
                                  ymid, nullptr, BATCH, MID_D, H_D, stream);
    if (i < L_N - 1)
      launch_mfma<1, 0, 0, 1, 0, 0>(ymid, fc2_bf + (size_t)i * H_D * MID_D, nullptr, h,
                                    h, nullptr, BATCH, H_D, MID_D, stream);
    else  // last layer: also emit bf16 h for the bilinear head
      launch_mfma<1, 0, 0, 1, 0, 1>(ymid, fc2_bf + (size_t)i * H_D * MID_D, nullptr, h,
                                    h, h_bf, BATCH, H_D, MID_D, stream);
  }

  // 5) bilinear head (bf16) + gene einsum (fp32 out, XCD-swizzled 1D grid)
  launch_mfma<2, 0, 1, 0, 0, 0>(h_bf, wbil_bf, nullptr, nullptr, blin, nullptr,
                                BATCH, C_N * R_D, H_D, stream);
  {
    int gx = (BATCH * C_N) / 128;            // 96
    int gy = (G_N + 127) / 128;              // 52
    int nwg = gx * gy;                       // 4992 (divisible by 8)
    gemm_mfma_kernel<2, 0, 0, 0, 0, 0, 1><<<nwg, 256, 0, stream>>>(
        blin, gene_bf, nullptr, nullptr, out, nullptr, BATCH * C_N, G_N, R_D, gx);
  }
}

// Round 5
// 640.064 us; speedup vs baseline: 8.0559x; 1.1438x over previous
//
#include <hip/hip_runtime.h>
#include <hip/hip_bf16.h>

#define N_NODES 19000
#define N_EDGES 600000
#define BATCH   4096
#define GNN_D   256
#define H_D     512
#define MID_D   2048
#define L_N     6
#define C_N     3
#define R_D     512
#define G_N     6640
#define LN_EPS  1e-5f
#define MAXDEG  128

typedef __attribute__((ext_vector_type(8))) short short8;
typedef __attribute__((ext_vector_type(4))) float f32x4;
typedef __hip_bfloat16 bf16;

// ---------------- small utility kernels ----------------

__global__ void f32_to_bf16_kernel(const float* __restrict__ in, bf16* __restrict__ out, int n4) {
  int i = blockIdx.x * blockDim.x + threadIdx.x;
  if (i >= n4) return;
  float4 v = ((const float4*)in)[i];
  out[i * 4 + 0] = __float2bfloat16(v.x);
  out[i * 4 + 1] = __float2bfloat16(v.y);
  out[i * 4 + 2] = __float2bfloat16(v.z);
  out[i * 4 + 3] = __float2bfloat16(v.w);
}

// combined [w_root | w_neigh] -> bf16 [GNN_D x 2*GNN_D]
__global__ void build_wrn_kernel(const float* __restrict__ w_root,
                                 const float* __restrict__ w_neigh,
                                 bf16* __restrict__ out) {
  int i4 = blockIdx.x * blockDim.x + threadIdx.x;
  if (i4 >= GNN_D * 2 * GNN_D / 4) return;
  int base = i4 * 4;
  int n = base >> 9;
  int k = base & 511;
  const float* src = (k < GNN_D) ? (w_root + (size_t)n * GNN_D + k)
                                 : (w_neigh + (size_t)n * GNN_D + (k - GNN_D));
  float4 v = *(const float4*)src;
  out[base + 0] = __float2bfloat16(v.x);
  out[base + 1] = __float2bfloat16(v.y);
  out[base + 2] = __float2bfloat16(v.z);
  out[base + 3] = __float2bfloat16(v.w);
}

__global__ void init_meta_kernel(int* __restrict__ flags, int* __restrict__ cursor,
                                 int* __restrict__ nuniq) {
  int i = blockIdx.x * blockDim.x + threadIdx.x;
  if (i < N_NODES) flags[i] = 0;
  if (i < BATCH) cursor[i] = 0;
  if (i == 0) *nuniq = 0;
}

__global__ void mark_needed_kernel(const int* __restrict__ idx, int* __restrict__ flags) {
  int i = blockIdx.x * blockDim.x + threadIdx.x;
  if (i < BATCH) {
    int id = idx[i];
    if (id >= 0) flags[id] = 1;
  }
}

__global__ void assign_slots_kernel(const int* __restrict__ flags, int* __restrict__ slot,
                                    int* __restrict__ uniq, int* __restrict__ nuniq) {
  int i = blockIdx.x * blockDim.x + threadIdx.x;
  if (i >= N_NODES) return;
  if (flags[i]) {
    int s = atomicAdd(nuniq, 1);
    slot[i] = s;
    uniq[s] = i;
  }
}

__global__ __launch_bounds__(256) void fill_edges_kernel(
    const int* __restrict__ ei, const float* __restrict__ ew,
    const int* __restrict__ flags, const int* __restrict__ slot,
    int* __restrict__ cursor, int* __restrict__ el_src, float* __restrict__ el_w) {
  int e = blockIdx.x * blockDim.x + threadIdx.x;
  if (e >= N_EDGES) return;
  int dst = ei[N_EDGES + e];
  if (!flags[dst]) return;
  int s = slot[dst];
  int p = atomicAdd(&cursor[s], 1);
  if (p < MAXDEG) {
    el_src[s * MAXDEG + p] = ei[e];
    el_w[s * MAXDEG + p] = ew[e];
  }
}

// one block per slot: compact2[s] = [ cache[uniq[s]] | sum_e w_e*cache[src_e] ]  (bf16)
__global__ __launch_bounds__(256) void gather_nodes_kernel(
    const float* __restrict__ cache, const int* __restrict__ uniq,
    const int* __restrict__ cursor, const int* __restrict__ nuniq,
    const int* __restrict__ el_src, const float* __restrict__ el_w,
    bf16* __restrict__ compact2) {
  int s = blockIdx.x, t = threadIdx.x;
  bf16* row = compact2 + (size_t)s * (2 * GNN_D);
  if (s >= *nuniq) {
    row[t] = __float2bfloat16(0.f);
    row[GNN_D + t] = __float2bfloat16(0.f);
    return;
  }
  row[t] = __float2bfloat16(cache[(size_t)uniq[s] * GNN_D + t]);
  int deg = cursor[s];
  deg = (deg < MAXDEG) ? deg : MAXDEG;
  float acc = 0.f;
  for (int e = 0; e < deg; ++e) {
    int src = el_src[s * MAXDEG + e];
    float w = el_w[s * MAXDEG + e];
    acc += cache[(size_t)src * GNN_D + t] * w;
  }
  row[GNN_D + t] = __float2bfloat16(acc);
}

// gather (with -1 fallback) + LayerNorm over 256 -> bf16
__global__ __launch_bounds__(256) void gather_ln_kernel(
    const float* __restrict__ embc, const int* __restrict__ slot,
    const float* __restrict__ fallback, const int* __restrict__ idx,
    const float* __restrict__ scale, const float* __restrict__ bias,
    bf16* __restrict__ out) {
  int b = blockIdx.x, t = threadIdx.x;
  int id = idx[b];
  float v = (id >= 0) ? embc[(size_t)slot[id] * GNN_D + t] : fallback[t];
  float s = v, q = v * v;
#pragma unroll
  for (int o = 32; o > 0; o >>= 1) { s += __shfl_down(s, o); q += __shfl_down(q, o); }
  __shared__ float ls[4], lq[4];
  int wv = t >> 6, ln = t & 63;
  if (ln == 0) { ls[wv] = s; lq[wv] = q; }
  __syncthreads();
  s = ls[0] + ls[1] + ls[2] + ls[3];
  q = lq[0] + lq[1] + lq[2] + lq[3];
  float mu = s * (1.f / GNN_D);
  float var = q * (1.f / GNN_D) - mu * mu;
  float r = rsqrtf(var + LN_EPS);
  out[(size_t)b * GNN_D + t] = __float2bfloat16((v - mu) * r * scale[t] + bias[t]);
}

// LayerNorm over 512 -> bf16
__global__ __launch_bounds__(256) void ln512_kernel(
    const float* __restrict__ x, const float* __restrict__ scale,
    const float* __restrict__ bias, bf16* __restrict__ out) {
  int b = blockIdx.x, t = threadIdx.x;
  const float* xr = x + (size_t)b * H_D;
  float v0 = xr[t];
  float v1 = xr[256 + t];
  float s = v0 + v1, q = v0 * v0 + v1 * v1;
#pragma unroll
  for (int o = 32; o > 0; o >>= 1) { s += __shfl_down(s, o); q += __shfl_down(q, o); }
  __shared__ float ls[4], lq[4];
  int wv = t >> 6, ln = t & 63;
  if (ln == 0) { ls[wv] = s; lq[wv] = q; }
  __syncthreads();
  s = ls[0] + ls[1] + ls[2] + ls[3];
  q = lq[0] + lq[1] + lq[2] + lq[3];
  float mu = s * (1.f / H_D);
  float var = q * (1.f / H_D) - mu * mu;
  float r = rsqrtf(var + LN_EPS);
  bf16* orow = out + (size_t)b * H_D;
  orow[t]       = __float2bfloat16((v0 - mu) * r * scale[t]       + bias[t]);
  orow[256 + t] = __float2bfloat16((v1 - mu) * r * scale[256 + t] + bias[256 + t]);
}

__device__ inline float gelu_exact(float x) {
  return 0.5f * x * (1.f + erff(x * 0.70710678118654752f));
}

// ---------------- bf16 MFMA GEMM: C = act(A @ W^T [+ bias] [+ addC]) ----------------
// A: [M,K] bf16 row-major, W: [N,K] bf16 row-major. M % BM == 0, K % 32 == 0.
// BM=NBM*64, BN=NBN*64; 4 waves (2x2): wave owns (NBM*32) x (NBN*32).
// 2-phase double-buffered K-loop (T3 minimum): issue next-tile global_load_lds
// into buf^1 BEFORE ds_read+MFMA of buf; single vmcnt(0)+barrier per K-step.

template <int NBM, int NBN, int ACT, int OUT_BF16, int ADDC, int BIAS, int HBF, int SWZ>
__global__ __launch_bounds__(256) void gemm_mfma_kernel(
    const bf16* __restrict__ A, const bf16* __restrict__ W,
    const float* __restrict__ bias, const float* __restrict__ addC,
    void* __restrict__ Cout, bf16* __restrict__ out2,
    int M, int N, int K, int gx) {
  constexpr int BM = NBM * 64;
  constexpr int BN = NBN * 64;
  constexpr int NF_M = NBM * 2;    // 16-row m-fragments per wave
  constexpr int NF_N = NBN * 2;    // 16-col n-fragments per wave
  __shared__ __align__(16) bf16 sA[2][BM * 32];
  __shared__ __align__(16) bf16 sB[2][BN * 32];
  const int tid = threadIdx.x;
  const int lane = tid & 63;
  const int wid = tid >> 6;
  const int wr = wid >> 1, wc = wid & 1;

  int bidx, bidy;
  if (SWZ) {
    int nwg = gridDim.x;
    int bid = blockIdx.x;
    int q = nwg >> 3, r = nwg & 7;
    int xcd = bid & 7, orig = bid >> 3;
    int swz = (xcd < r ? xcd * (q + 1) : r * (q + 1) + (xcd - r) * q) + orig;
    bidx = swz % gx;
    bidy = swz / gx;
  } else {
    bidx = blockIdx.x;
    bidy = blockIdx.y;
  }
  const int bm = bidx * BM, bn = bidy * BN;

  f32x4 acc[NF_M][NF_N];
#pragma unroll
  for (int m = 0; m < NF_M; ++m)
#pragma unroll
    for (int n = 0; n < NF_N; ++n) acc[m][n] = (f32x4){0.f, 0.f, 0.f, 0.f};

  const int rbase = lane & 15;
  const int g = lane >> 4;
  const int kq = (tid & 3) << 3;    // per-thread k offset within 32-chunk

  // precomputed clamped global rows for each staging chunk
  int arow[NBM], brow[NBN];
#pragma unroll
  for (int i = 0; i < NBM; ++i) {
    int r0 = bm + ((i * 256 + tid) >> 2);
    arow[i] = (r0 < M) ? r0 : (M - 1);
  }
#pragma unroll
  for (int i = 0; i < NBN; ++i) {
    int r0 = bn + ((i * 256 + tid) >> 2);
    brow[i] = (r0 < N) ? r0 : (N - 1);
  }

  auto stage = [&](int buf, int k0) {
#pragma unroll
    for (int i = 0; i < NBM; ++i)
      __builtin_amdgcn_global_load_lds(
          (const __attribute__((address_space(1))) void*)(A + (size_t)arow[i] * K + k0 + kq),
          (__attribute__((address_space(3))) void*)(&sA[buf][(i * 256 + tid) * 8]), 16, 0, 0);
#pragma unroll
    for (int i = 0; i < NBN; ++i)
      __builtin_amdgcn_global_load_lds(
          (const __attribute__((address_space(1))) void*)(W + (size_t)brow[i] * K + k0 + kq),
          (__attribute__((address_space(3))) void*)(&sB[buf][(i * 256 + tid) * 8]), 16, 0, 0);
  };

  const int NT = K >> 5;
  stage(0, 0);
  __syncthreads();               // drain prologue stage

  int cur = 0;
  for (int t = 0; t < NT; ++t) {
    if (t + 1 < NT) stage(cur ^ 1, (t + 1) << 5);   // issue next tile early

    short8 af[NF_M], bfrag[NF_N];
#pragma unroll
    for (int m = 0; m < NF_M; ++m)
      af[m] = *(const short8*)(&sA[cur][(wr * (NBM * 32) + m * 16 + rbase) * 32 + g * 8]);
#pragma unroll
    for (int n = 0; n < NF_N; ++n)
      bfrag[n] = *(const short8*)(&sB[cur][(wc * (NBN * 32) + n * 16 + rbase) * 32 + g * 8]);
#pragma unroll
    for (int m = 0; m < NF_M; ++m)
#pragma unroll
      for (int n = 0; n < NF_N; ++n)
        acc[m][n] = __builtin_amdgcn_mfma_f32_16x16x32_bf16(af[m], bfrag[n], acc[m][n], 0, 0, 0);

    __syncthreads();             // one vmcnt(0)+barrier per K-step
    cur ^= 1;
  }

  // C/D frag mapping: col = lane&15, row = (lane>>4)*4 + reg   [m89-verified]
  const int rb = (lane >> 4) * 4;
  const int cb = lane & 15;
#pragma unroll
  for (int m = 0; m < NF_M; ++m) {
#pragma unroll
    for (int n = 0; n < NF_N; ++n) {
      int col = bn + wc * (NBN * 32) + n * 16 + cb;
      if (col >= N) continue;
      int row0 = bm + wr * (NBM * 32) + m * 16 + rb;
#pragma unroll
      for (int r = 0; r < 4; ++r) {
        int row = row0 + r;
        if (row >= M) continue;
        float v = acc[m][n][r];
        if (BIAS) v += bias[col];
        if (ADDC) v += addC[(size_t)row * N + col];
        if (ACT == 1) v = fmaxf(v, 0.f);
        if (ACT == 2) v = gelu_exact(v);
        if (OUT_BF16)
          ((bf16*)Cout)[(size_t)row * N + col] = __float2bfloat16(v);
        else
          ((float*)Cout)[(size_t)row * N + col] = v;
        if (HBF)
          out2[(size_t)row * N + col] = __float2bfloat16(v);
      }
    }
  }
}

template <int NBM, int NBN, int ACT, int OUT_BF16, int ADDC, int BIAS, int HBF>
static void launch_mfma(const bf16* A, const bf16* W, const float* bias,
                        const float* addC, void* C, bf16* out2,
                        int M, int N, int K, hipStream_t stream) {
  dim3 grid(M / (NBM * 64), (N + NBN * 64 - 1) / (NBN * 64));
  gemm_mfma_kernel<NBM, NBN, ACT, OUT_BF16, ADDC, BIAS, HBF, 0>
      <<<grid, 256, 0, stream>>>(A, W, bias, addC, C, out2, M, N, K, 0);
}

// ---------------- launch ----------------

#define MB (1024u * 1024u)

extern "C" void kernel_launch(void* const* d_in, const int* in_sizes, int n_in,
                              void* d_out, int out_size, void* d_ws, size_t ws_size,
                              hipStream_t stream) {
  const int*   node_indices = (const int*)d_in[0];
  const int*   edge_index   = (const int*)d_in[1];
  const float* edge_weight  = (const float*)d_in[2];
  const float* cache        = (const float*)d_in[3];
  const float* w_root       = (const float*)d_in[4];
  const float* w_neigh      = (const float*)d_in[5];
  const float* w_post       = (const float*)d_in[6];
  const float* b_post       = (const float*)d_in[7];
  const float* fallback     = (const float*)d_in[8];
  const float* ln_in_scale  = (const float*)d_in[9];
  const float* ln_in_bias   = (const float*)d_in[10];
  const float* w_in         = (const float*)d_in[11];
  const float* rb_ln_scale  = (const float*)d_in[12];
  const float* rb_ln_bias   = (const float*)d_in[13];
  const float* rb_fc1       = (const float*)d_in[14];
  const float* rb_fc2       = (const float*)d_in[15];
  const float* w_bil        = (const float*)d_in[16];
  const float* gene         = (const float*)d_in[17];
  float* out = (float*)d_out;

  char* w = (char*)d_ws;
  // --- region A (0..24 MB): graph-stage buffers, dead after gather_ln; ymid aliases ---
  bf16*  compact2 = (bf16*)(w + 0 * MB);   // 4 MB
  bf16*  tmpc     = (bf16*)(w + 4 * MB);   // 2 MB
  float* embc     = (float*)(w + 6 * MB);  // 4 MB
  int*   el_src   = (int*)  (w + 10 * MB); // 2 MB
  float* el_w     = (float*)(w + 12 * MB); // 2 MB
  int*   flags    = (int*)  (w + 14 * MB);
  int*   slot     = (int*)  (w + 14 * MB + 80 * 1024);
  int*   uniq     = (int*)  (w + 14 * MB + 160 * 1024);
  int*   cursor   = (int*)  (w + 14 * MB + 180 * 1024);
  int*   nuniq    = (int*)  (w + 14 * MB + 200 * 1024);
  bf16*  ymid     = (bf16*) (w + 0 * MB);  // 16 MB (phase-4 only, region A dead)
  // --- region B (24 MB..): activations + bf16 weights ---
  bf16*  pertln  = (bf16*) (w + 24 * MB);
  float* h       = (float*)(w + 26 * MB);
  bf16*  yln     = (bf16*) (w + 34 * MB);
  bf16*  h_bf    = (bf16*) (w + 38 * MB);
  bf16*  blin    = (bf16*) (w + 42 * MB);
  bf16*  w_in_bf = (bf16*) (w + 55 * MB);
  bf16*  fc1_bf  = (bf16*) (w + 56 * MB);
  bf16*  fc2_bf  = (bf16*) (w + 68 * MB);
  bf16*  wbil_bf = (bf16*) (w + 80 * MB);
  bf16*  gene_bf = (bf16*) (w + 82 * MB);
  bf16*  wrn_bf  = (bf16*) (w + 90 * MB);
  bf16*  wpost_bf= (bf16*) (w + 91 * MB);

  // 0) weight conversions to bf16
  {
    int n4;
    n4 = H_D * GNN_D / 4;
    f32_to_bf16_kernel<<<(n4 + 255) / 256, 256, 0, stream>>>(w_in, w_in_bf, n4);
    n4 = L_N * MID_D * H_D / 4;
    f32_to_bf16_kernel<<<(n4 + 255) / 256, 256, 0, stream>>>(rb_fc1, fc1_bf, n4);
    f32_to_bf16_kernel<<<(n4 + 255) / 256, 256, 0, stream>>>(rb_fc2, fc2_bf, n4);
    n4 = C_N * R_D * H_D / 4;
    f32_to_bf16_kernel<<<(n4 + 255) / 256, 256, 0, stream>>>(w_bil, wbil_bf, n4);
    n4 = G_N * R_D / 4;
    f32_to_bf16_kernel<<<(n4 + 255) / 256, 256, 0, stream>>>(gene, gene_bf, n4);
    n4 = GNN_D * GNN_D / 4;
    f32_to_bf16_kernel<<<(n4 + 255) / 256, 256, 0, stream>>>(w_post, wpost_bf, n4);
    int nw = GNN_D * 2 * GNN_D / 4;
    build_wrn_kernel<<<(nw + 255) / 256, 256, 0, stream>>>(w_root, w_neigh, wrn_bf);
  }

  // 1) compact-slot construction + bucketed edge lists + gather-accumulate (bf16 out)
  init_meta_kernel<<<(N_NODES + 255) / 256, 256, 0, stream>>>(flags, cursor, nuniq);
  mark_needed_kernel<<<(BATCH + 255) / 256, 256, 0, stream>>>(node_indices, flags);
  assign_slots_kernel<<<(N_NODES + 255) / 256, 256, 0, stream>>>(flags, slot, uniq, nuniq);
  fill_edges_kernel<<<(N_EDGES + 255) / 256, 256, 0, stream>>>(
      edge_index, edge_weight, flags, slot, cursor, el_src, el_w);
  gather_nodes_kernel<<<BATCH, 256, 0, stream>>>(
      cache, uniq, cursor, nuniq, el_src, el_w, compact2);

  // 2) compact graph tail (bf16 MFMA, BM=64): relu([cache|agg]@[wr|wn]^T) @ w_post^T + b
  launch_mfma<1, 1, 1, 1, 0, 0, 0>(compact2, wrn_bf, nullptr, nullptr, tmpc, nullptr,
                                   BATCH, GNN_D, 2 * GNN_D, stream);
  launch_mfma<1, 1, 0, 0, 0, 1, 0>(tmpc, wpost_bf, b_post, nullptr, embc, nullptr,
                                   BATCH, GNN_D, GNN_D, stream);

  // 3) gather + input LN (bf16 out), input proj (BM=64, BN=64) -> h fp32
  gather_ln_kernel<<<BATCH, 256, 0, stream>>>(embc, slot, fallback, node_indices,
                                              ln_in_scale, ln_in_bias, pertln);
  launch_mfma<1, 1, 0, 0, 0, 0, 0>(pertln, w_in_bf, nullptr, nullptr, h, nullptr,
                                   BATCH, H_D, GNN_D, stream);

  // 4) residual blocks: LN -> fc1(gelu, bf16, 128x128) -> fc2(+h, fp32, 64x64)
  for (int i = 0; i < L_N; ++i) {
    ln512_kernel<<<BATCH, 256, 0, stream>>>(h, rb_ln_scale + (size_t)i * H_D,
                                            rb_ln_bias + (size_t)i * H_D, yln);
    launch_mfma<2, 2, 2, 1, 0, 0, 0>(yln, fc1_bf + (size_t)i * MID_D * H_D, nullptr, nullptr,
                                     ymid, nullptr, BATCH, MID_D, H_D, stream);
    if (i < L_N - 1)
      launch_mfma<1, 1, 0, 0, 1, 0, 0>(ymid, fc2_bf + (size_t)i * H_D * MID_D, nullptr, h,
                                       h, nullptr, BATCH, H_D, MID_D, stream);
    else  // last layer: also emit bf16 h for the bilinear head
      launch_mfma<1, 1, 0, 0, 1, 0, 1>(ymid, fc2_bf + (size_t)i * H_D * MID_D, nullptr, h,
                                       h, h_bf, BATCH, H_D, MID_D, stream);
  }

  // 5) bilinear head (64x128, bf16 out) + gene einsum (128x128, fp32 out, XCD swizzle)
  launch_mfma<1, 2, 0, 1, 0, 0, 0>(h_bf, wbil_bf, nullptr, nullptr, blin, nullptr,
                                   BATCH, C_N * R_D, H_D, stream);
  {
    int gx = (BATCH * C_N) / 128;            // 96
    int gy = (G_N + 127) / 128;              // 52
    int nwg = gx * gy;                       // 4992 (divisible by 8)
    gemm_mfma_kernel<2, 2, 0, 0, 0, 0, 0, 1><<<nwg, 256, 0, stream>>>(
        blin, gene_bf, nullptr, nullptr, out, nullptr, BATCH * C_N, G_N, R_D, gx);
  }
}